// Round 2
// baseline (701.100 us; speedup 1.0000x reference)
//
#include <hip/hip_runtime.h>
#include <math.h>

#define N_NODES 40000
#define N_EDGES 640000
#define D 128
#define H 8
#define C 16
#define NBG 1250     // 40000/32 exactly
#define KP 136       // sA k-stride (bf16 elems)
#define NBUCK 625    // 64-node buckets: bucket = dst >> 6 (40000 = 625*64)
#define NHIST 64     // histogram chunks (10000 edges each)
#define ECH_H 10000
#define NFILL 160    // fill chunks (4000 edges each)
#define ECH_F 4000
#define AW 136       // k_agg LDS row stride: 128 ch + 8 ssum

typedef __attribute__((ext_vector_type(8))) short short8;   // 8 bf16 (4 VGPRs)
typedef __attribute__((ext_vector_type(4))) float floatx4;  // MFMA C/D

// ws layout (float offsets):
//  xh    : 0          .. 2,560,000   (N*128 bf16 stored as ushort)
//  al    : 5,120,000  .. 5,440,000   (N*8)
//  ar    : 5,440,000  .. 5,760,000   (N*8)
//  pexph : 5,760,000  .. 8,320,000   (E*8 bf16 ushort, bucket-grouped exp(logit))
//  meta  : 10,880,000 .. 11,520,000  (E ints, bucket-grouped (dlocal<<16)|src)
//  gcnt  : 11,600,000 .. +625        (per-bucket totals)      | zeroed together
//  gcur  : 11,600,625 .. +625        (per-bucket cursors)     | (one memset)
//  gbase : 11,602,000 .. +625        (per-bucket exclusive scan)
//  wt    : 12,800,000 .. +8,192 floats (2x 128x128 bf16 transposed weights)

__device__ __forceinline__ unsigned short f2bf(float f) {
  const unsigned u = __float_as_uint(f);
  return (unsigned short)((u + 0x7FFFu + ((u >> 16) & 1u)) >> 16);  // RNE
}
__device__ __forceinline__ float bflo(unsigned p) {
  return __uint_as_float(p << 16);
}
__device__ __forceinline__ float bfhi(unsigned p) {
  return __uint_as_float(p & 0xFFFF0000u);
}
__device__ __forceinline__ float bf2f(unsigned short u) {
  return __uint_as_float((unsigned)u << 16);
}

// Pre-transpose W (fp32 [k][n]) -> wt (bf16 [g][n][k]). 64 KB total.
__global__ void k_prep(const float* __restrict__ Wlin,
                       const float* __restrict__ Wres,
                       unsigned short* __restrict__ wt)
{
  const int n = blockIdx.x, k = threadIdx.x, g = blockIdx.y;
  const float* W = g ? Wres : Wlin;
  wt[((g * 128 + n) * 128) + k] = f2bf(W[(long)k * 128 + n]);
}

// MFMA bf16 GEMM, 32-row blocks. blockIdx.y: 0 = xh=bf16(feat@Wlin) + fused
// alpha epilogue; 1 = outp=feat@Wres; 2 = bucket histogram (64 blocks, LDS
// 625-bin hist, one global atomic per (block,bin) => 40K atomics vs 640K).
__global__ __launch_bounds__(256, 8) void k_gemm(
    const float* __restrict__ feat, const unsigned short* __restrict__ wt,
    unsigned short* __restrict__ xh, float* __restrict__ outp,
    const int* __restrict__ dst, int* __restrict__ gcnt,
    const float* __restrict__ attl, const float* __restrict__ attr,
    float* __restrict__ al, float* __restrict__ ar)
{
  __shared__ float smemf[32 * 132];   // 16,896 B; sA uses first 8,704 B
  const int t = threadIdx.x;

  if (blockIdx.y == 2) {              // bucket histogram
    if (blockIdx.x >= NHIST) return;
    int* lcnt = (int*)smemf;          // 625 ints
    for (int i = t; i < NBUCK; i += 256) lcnt[i] = 0;
    __syncthreads();
    const int e0 = blockIdx.x * ECH_H;
    for (int e = e0 + t; e < e0 + ECH_H; e += 256)
      atomicAdd(&lcnt[dst[e] >> 6], 1);
    __syncthreads();
    for (int i = t; i < NBUCK; i += 256) {
      const int c = lcnt[i];
      if (c) atomicAdd(&gcnt[i], c);
    }
    return;
  }

  short* sA = (short*)smemf;          // [32][KP]
  float* sD = smemf;                  // [32][132]
  const int row0 = blockIdx.x * 32;
  const int g = blockIdx.y;

  // stage A: 32 rows x 128 k, fp32 -> bf16 (coalesced float4 reads)
  {
    const int kq = t & 31;            // k = kq*4
    const int rb = (t >> 5) * 4;      // 4 rows per thread
    #pragma unroll
    for (int i = 0; i < 4; ++i) {
      const int r = rb + i;
      const float4 f = *(const float4*)&feat[(long)(row0 + r) * 128 + kq * 4];
      const unsigned lo = (unsigned)f2bf(f.x) | ((unsigned)f2bf(f.y) << 16);
      const unsigned hi = (unsigned)f2bf(f.z) | ((unsigned)f2bf(f.w) << 16);
      *(uint2*)&sA[r * KP + kq * 4] = make_uint2(lo, hi);
    }
  }

  const int w = t >> 6, lane = t & 63;
  const int c15 = lane & 15, q = lane >> 4;

  // B frags: wave w owns n-tiles {2w, 2w+1}
  short8 bfr[4][2];
  const unsigned short* Wt = wt + g * 16384;
  #pragma unroll
  for (int kc = 0; kc < 4; ++kc)
    #pragma unroll
    for (int nt = 0; nt < 2; ++nt) {
      const int n = (w * 2 + nt) * 16 + c15;
      bfr[kc][nt] = *(const short8*)&Wt[n * 128 + kc * 32 + q * 8];
    }
  __syncthreads();

  floatx4 acc[2][2];
  #pragma unroll
  for (int mt = 0; mt < 2; ++mt) {
    acc[mt][0] = (floatx4){0.f, 0.f, 0.f, 0.f};
    acc[mt][1] = (floatx4){0.f, 0.f, 0.f, 0.f};
  }
  #pragma unroll
  for (int kc = 0; kc < 4; ++kc)
    #pragma unroll
    for (int mt = 0; mt < 2; ++mt) {
      const short8 afr = *(const short8*)&sA[(mt * 16 + c15) * KP + kc * 32 + q * 8];
      acc[mt][0] = __builtin_amdgcn_mfma_f32_16x16x32_bf16(afr, bfr[kc][0], acc[mt][0], 0, 0, 0);
      acc[mt][1] = __builtin_amdgcn_mfma_f32_16x16x32_bf16(afr, bfr[kc][1], acc[mt][1], 0, 0, 0);
    }
  __syncthreads();   // sA dead

  // D -> sD[32][132] (2-way banks, free)
  #pragma unroll
  for (int mt = 0; mt < 2; ++mt)
    #pragma unroll
    for (int nt = 0; nt < 2; ++nt) {
      const int col = (w * 2 + nt) * 16 + c15;
      #pragma unroll
      for (int r = 0; r < 4; ++r)
        sD[(mt * 16 + q * 4 + r) * 132 + col] = acc[mt][nt][r];
    }
  __syncthreads();

  // coalesced stores: thread -> (row = t>>3, 16-col segment = t&7)
  const int orow = t >> 3, seg = t & 7;
  const int grow = row0 + orow;
  if (g == 0) {
    #pragma unroll
    for (int i = 0; i < 2; ++i) {     // 8 cols per iter
      const float4 v0 = *(const float4*)&sD[orow * 132 + seg * 16 + i * 8];
      const float4 v1 = *(const float4*)&sD[orow * 132 + seg * 16 + i * 8 + 4];
      uint4 u;
      u.x = (unsigned)f2bf(v0.x) | ((unsigned)f2bf(v0.y) << 16);
      u.y = (unsigned)f2bf(v0.z) | ((unsigned)f2bf(v0.w) << 16);
      u.z = (unsigned)f2bf(v1.x) | ((unsigned)f2bf(v1.y) << 16);
      u.w = (unsigned)f2bf(v1.z) | ((unsigned)f2bf(v1.w) << 16);
      *(uint4*)&xh[(long)grow * 128 + seg * 16 + i * 8] = u;
    }
    // fused alpha epilogue: thread = (node orow, head seg); one 16-dot each.
    const int h = seg;
    float sl = 0.f, sr = 0.f;
    #pragma unroll
    for (int c4 = 0; c4 < 4; ++c4) {
      const float4 xv = *(const float4*)&sD[orow * 132 + h * 16 + c4 * 4];
      const float4 lv = *(const float4*)&attl[h * 16 + c4 * 4];
      const float4 rv = *(const float4*)&attr[h * 16 + c4 * 4];
      sl += xv.x * lv.x + xv.y * lv.y + xv.z * lv.z + xv.w * lv.w;
      sr += xv.x * rv.x + xv.y * rv.y + xv.z * rv.z + xv.w * rv.w;
    }
    al[(long)grow * 8 + h] = sl;
    ar[(long)grow * 8 + h] = sr;
  } else {
    #pragma unroll
    for (int i = 0; i < 4; ++i) {
      const float4 v = *(const float4*)&sD[orow * 132 + seg * 16 + i * 4];
      *(float4*)&outp[(long)grow * 128 + seg * 16 + i * 4] = v;
    }
  }
}

// Exclusive scan of 625 bucket totals (single block).
__global__ __launch_bounds__(1024) void k_scan_g(
    const int* __restrict__ gcnt, int* __restrict__ gbase)
{
  __shared__ int sd[1024];
  const int t = threadIdx.x;
  const int v = (t < NBUCK) ? gcnt[t] : 0;
  sd[t] = v;
  __syncthreads();
  #pragma unroll
  for (int off = 1; off < 1024; off <<= 1) {
    const int add = (t >= off) ? sd[t - off] : 0;
    __syncthreads();
    sd[t] += add;
    __syncthreads();
  }
  if (t < NBUCK) gbase[t] = sd[t] - v;
}

// Two-pass fill per 4000-edge chunk: (1) LDS bucket counts, (2) one reserve
// atomic per (block,bucket) (~100K total), (3) recompute + scatter into the
// block's contiguous per-bucket runs (avg 6.4 slots => coalesced 16B writes).
// No per-edge global atomics. pexp: no max subtraction (logits bounded ~|4|,
// softmax shift-invariant — validated in earlier rounds).
__global__ __launch_bounds__(512) void k_fill(
    const int* __restrict__ src, const int* __restrict__ dst,
    const float* __restrict__ ew, const float* __restrict__ al,
    const float* __restrict__ ar, const int* __restrict__ gbase,
    int* __restrict__ gcur,
    unsigned short* __restrict__ pexph, int* __restrict__ meta)
{
  __shared__ int lcnt[NBUCK];   // pass1 counts, reused as pass2 cursor
  __shared__ int lbase[NBUCK];
  const int t = threadIdx.x;
  for (int i = t; i < NBUCK; i += 512) lcnt[i] = 0;
  __syncthreads();
  const int e0 = blockIdx.x * ECH_F;
  for (int e = e0 + t; e < e0 + ECH_F; e += 512)
    atomicAdd(&lcnt[dst[e] >> 6], 1);
  __syncthreads();
  for (int i = t; i < NBUCK; i += 512) {
    const int c = lcnt[i];
    lbase[i] = c ? (gbase[i] + atomicAdd(&gcur[i], c)) : 0;
    lcnt[i] = 0;
  }
  __syncthreads();
  for (int e = e0 + t; e < e0 + ECH_F; e += 512) {
    const int s = src[e], d = dst[e];
    const float w = ew[e];
    const float4 l0 = *(const float4*)&al[(long)s * 8];
    const float4 l1 = *(const float4*)&al[(long)s * 8 + 4];
    const float4 r0 = *(const float4*)&ar[(long)d * 8];
    const float4 r1 = *(const float4*)&ar[(long)d * 8 + 4];
    float lv[8] = {l0.x + r0.x, l0.y + r0.y, l0.z + r0.z, l0.w + r0.w,
                   l1.x + r1.x, l1.y + r1.y, l1.z + r1.z, l1.w + r1.w};
    #pragma unroll
    for (int h = 0; h < 8; ++h) {
      float a = w * lv[h];
      a = (a >= 0.f) ? a : 0.2f * a;   // leaky_relu(0.2)
      lv[h] = __expf(a);
    }
    const int b = d >> 6;
    const int p = lbase[b] + atomicAdd(&lcnt[b], 1);   // LDS atomic only
    meta[p] = ((d & 63) << 16) | s;
    uint4 u;
    u.x = (unsigned)f2bf(lv[0]) | ((unsigned)f2bf(lv[1]) << 16);
    u.y = (unsigned)f2bf(lv[2]) | ((unsigned)f2bf(lv[3]) << 16);
    u.z = (unsigned)f2bf(lv[4]) | ((unsigned)f2bf(lv[5]) << 16);
    u.w = (unsigned)f2bf(lv[6]) | ((unsigned)f2bf(lv[7]) << 16);
    *(uint4*)&pexph[(long)p * 8] = u;
  }
}

// One block per 64-node bucket. LDS fp32 accumulators acc[64][136]
// (128 ch + 8 softmax denominators), combined via ds_add_f32 (2-way bank
// aliasing = free). Normalize + ELU + residual add in the epilogue.
__global__ __launch_bounds__(256, 4) void k_agg(
    const int* __restrict__ gbase, const int* __restrict__ gcnt,
    const int* __restrict__ meta, const unsigned short* __restrict__ pexph,
    const unsigned short* __restrict__ xh, float* __restrict__ outp)
{
  __shared__ float acc[64 * AW];   // 34,816 B
  const int b = blockIdx.x;
  const int cntb = gcnt[b];
  if (cntb == 0) return;           // all 64 nodes keep residual
  const int start = gbase[b];
  const int end = start + cntb;
  const int t = threadIdx.x;
  for (int i = t; i < 64 * AW; i += 256) acc[i] = 0.f;
  __syncthreads();

  const int wave = t >> 6, lane = t & 63;
  const int h = lane >> 3;
  const int co = lane * 2;

  auto edge_body = [&](int p) {
    const unsigned m = (unsigned)meta[p];
    const int s = m & 0xFFFF;
    const int dl = m >> 16;
    const float ev = bf2f(pexph[(long)p * 8 + h]);
    const unsigned v = *(const unsigned*)&xh[(long)s * 128 + co];
    float* arow = &acc[dl * AW];
    atomicAdd(&arow[co], bflo(v) * ev);
    atomicAdd(&arow[co + 1], bfhi(v) * ev);
    if ((lane & 7) == 0) atomicAdd(&arow[128 + h], ev);
  };

  int p = start + wave;
  for (; p + 4 < end; p += 8) { edge_body(p); edge_body(p + 4); }
  if (p < end) edge_body(p);
  __syncthreads();

  // finalize: thread -> (node t>>2, 32-channel quarter (t&3)*32)
  const int dl = t >> 2, cq = (t & 3) * 32;
  const int dnode = (b << 6) + dl;
  #pragma unroll
  for (int i = 0; i < 8; ++i) {
    const int c0 = cq + i * 4;
    const float ss = acc[dl * AW + 128 + (c0 >> 4)];
    if (ss > 0.f) {
      const float rs = 1.0f / ss;
      const float4 a = *(const float4*)&acc[dl * AW + c0];
      float4 o = *(float4*)&outp[(long)dnode * 128 + c0];
      const float ax = a.x * rs, ay = a.y * rs, az = a.z * rs, aw = a.w * rs;
      o.x += (ax > 0.f) ? ax : expm1f(ax);
      o.y += (ay > 0.f) ? ay : expm1f(ay);
      o.z += (az > 0.f) ? az : expm1f(az);
      o.w += (aw > 0.f) ? aw : expm1f(aw);
      *(float4*)&outp[(long)dnode * 128 + c0] = o;
    }
  }
}

extern "C" void kernel_launch(void* const* d_in, const int* in_sizes, int n_in,
                              void* d_out, int out_size, void* d_ws, size_t ws_size,
                              hipStream_t stream) {
  const float* feat = (const float*)d_in[0];
  const int*   eidx = (const int*)d_in[1];
  const float* ew   = (const float*)d_in[2];
  const float* Wlin = (const float*)d_in[3];
  const float* attl = (const float*)d_in[4];
  const float* attr = (const float*)d_in[5];
  const float* Wres = (const float*)d_in[6];
  float* outp = (float*)d_out;

  float* ws = (float*)d_ws;
  unsigned short* xh = (unsigned short*)ws;
  float* al   = ws + 5120000;
  float* ar   = ws + 5440000;
  unsigned short* pexph = (unsigned short*)(ws + 5760000);
  int*   meta = (int*)(ws + 10880000);
  int*   gcnt = (int*)(ws + 11600000);
  int*   gcur = gcnt + NBUCK;            // adjacent: one memset
  int*   gbase = (int*)(ws + 11602000);
  unsigned short* wt = (unsigned short*)(ws + 12800000);

  const int* src = eidx;
  const int* dst = eidx + N_EDGES;

  hipMemsetAsync(gcnt, 0, (size_t)2 * NBUCK * 4, stream);  // gcnt + gcur

  dim3 pgrid(128, 2);
  k_prep<<<pgrid, 128, 0, stream>>>(Wlin, Wres, wt);
  dim3 ggrid(NBG, 3);  // y=0 lin+alpha, y=1 res, y=2 bucket histogram
  k_gemm<<<ggrid, 256, 0, stream>>>(feat, wt, xh, outp, dst, gcnt,
                                    attl, attr, al, ar);
  k_scan_g<<<1, 1024, 0, stream>>>(gcnt, gbase);
  k_fill<<<NFILL, 512, 0, stream>>>(src, dst, ew, al, ar, gbase, gcur,
                                    pexph, meta);
  k_agg<<<NBUCK, 256, 0, stream>>>(gbase, gcnt, meta, pexph, xh, outp);
}

// Round 3
// 191.786 us; speedup vs baseline: 3.6556x; 3.6556x over previous
//
#include <hip/hip_runtime.h>
#include <math.h>

#define N_NODES 40000
#define N_EDGES 640000
#define D 128
#define H 8
#define C 16
#define NBG 1250     // 40000/32 exactly
#define KP 136       // sA k-stride (bf16 elems)
#define NBUCK 625    // 64-node buckets: bucket = dst >> 6 (40000 = 625*64)
#define NHIST 64     // histogram chunks (10000 edges each)
#define ECH_H 10000
#define NFILL 160    // fill chunks (4000 edges each)
#define ECH_F 4000
#define MAXB 1536    // bucket-size bound (mean 1024, sigma 32; 16-sigma guard)

typedef __attribute__((ext_vector_type(8))) short short8;   // 8 bf16 (4 VGPRs)
typedef __attribute__((ext_vector_type(4))) float floatx4;  // MFMA C/D

// ws layout (float offsets):
//  xh    : 0          .. 2,560,000   (N*128 bf16 stored as ushort)
//  al    : 5,120,000  .. 5,440,000   (N*8)
//  ar    : 5,440,000  .. 5,760,000   (N*8)
//  pexph : 5,760,000  .. 8,320,000   (E*8 bf16 ushort; bucket-grouped after
//                                     k_fill, node-sorted after k_sort)
//  meta  : 10,880,000 .. 11,520,000  (E ints; (dlocal<<16)|src after k_fill,
//                                     src after k_sort)
//  gcnt  : 11,600,000 .. +625        (per-bucket totals)   | zeroed together
//  gcur  : +625       .. +1250       (per-bucket cursors)  | (one memset)
//  gbase : 11,602,000 .. +625        (per-bucket exclusive scan)
//  nodeS : 11,700,000 .. +40,001     (per-node CSR starts, from k_sort)
//  wt    : 12,800,000 .. +8,192 floats (2x 128x128 bf16 transposed weights)

__device__ __forceinline__ unsigned short f2bf(float f) {
  const unsigned u = __float_as_uint(f);
  return (unsigned short)((u + 0x7FFFu + ((u >> 16) & 1u)) >> 16);  // RNE
}
__device__ __forceinline__ float bflo(unsigned p) {
  return __uint_as_float(p << 16);
}
__device__ __forceinline__ float bfhi(unsigned p) {
  return __uint_as_float(p & 0xFFFF0000u);
}
__device__ __forceinline__ float bf2f(unsigned short u) {
  return __uint_as_float((unsigned)u << 16);
}

// Pre-transpose W (fp32 [k][n]) -> wt (bf16 [g][n][k]). 64 KB total.
__global__ void k_prep(const float* __restrict__ Wlin,
                       const float* __restrict__ Wres,
                       unsigned short* __restrict__ wt)
{
  const int n = blockIdx.x, k = threadIdx.x, g = blockIdx.y;
  const float* W = g ? Wres : Wlin;
  wt[((g * 128 + n) * 128) + k] = f2bf(W[(long)k * 128 + n]);
}

// MFMA bf16 GEMM, 32-row blocks. blockIdx.y: 0 = xh=bf16(feat@Wlin) + fused
// alpha epilogue; 1 = outp=feat@Wres; 2 = bucket histogram (64 blocks, LDS
// 625-bin hist, one global atomic per (block,bin) => 40K atomics vs 640K).
__global__ __launch_bounds__(256, 8) void k_gemm(
    const float* __restrict__ feat, const unsigned short* __restrict__ wt,
    unsigned short* __restrict__ xh, float* __restrict__ outp,
    const int* __restrict__ dst, int* __restrict__ gcnt,
    const float* __restrict__ attl, const float* __restrict__ attr,
    float* __restrict__ al, float* __restrict__ ar)
{
  __shared__ float smemf[32 * 132];   // 16,896 B; sA uses first 8,704 B
  const int t = threadIdx.x;

  if (blockIdx.y == 2) {              // bucket histogram
    if (blockIdx.x >= NHIST) return;
    int* lcnt = (int*)smemf;          // 625 ints
    for (int i = t; i < NBUCK; i += 256) lcnt[i] = 0;
    __syncthreads();
    const int e0 = blockIdx.x * ECH_H;
    for (int e = e0 + t; e < e0 + ECH_H; e += 256)
      atomicAdd(&lcnt[dst[e] >> 6], 1);
    __syncthreads();
    for (int i = t; i < NBUCK; i += 256) {
      const int c = lcnt[i];
      if (c) atomicAdd(&gcnt[i], c);
    }
    return;
  }

  short* sA = (short*)smemf;          // [32][KP]
  float* sD = smemf;                  // [32][132]
  const int row0 = blockIdx.x * 32;
  const int g = blockIdx.y;

  // stage A: 32 rows x 128 k, fp32 -> bf16 (coalesced float4 reads)
  {
    const int kq = t & 31;            // k = kq*4
    const int rb = (t >> 5) * 4;      // 4 rows per thread
    #pragma unroll
    for (int i = 0; i < 4; ++i) {
      const int r = rb + i;
      const float4 f = *(const float4*)&feat[(long)(row0 + r) * 128 + kq * 4];
      const unsigned lo = (unsigned)f2bf(f.x) | ((unsigned)f2bf(f.y) << 16);
      const unsigned hi = (unsigned)f2bf(f.z) | ((unsigned)f2bf(f.w) << 16);
      *(uint2*)&sA[r * KP + kq * 4] = make_uint2(lo, hi);
    }
  }

  const int w = t >> 6, lane = t & 63;
  const int c15 = lane & 15, q = lane >> 4;

  // B frags: wave w owns n-tiles {2w, 2w+1}
  short8 bfr[4][2];
  const unsigned short* Wt = wt + g * 16384;
  #pragma unroll
  for (int kc = 0; kc < 4; ++kc)
    #pragma unroll
    for (int nt = 0; nt < 2; ++nt) {
      const int n = (w * 2 + nt) * 16 + c15;
      bfr[kc][nt] = *(const short8*)&Wt[n * 128 + kc * 32 + q * 8];
    }
  __syncthreads();

  floatx4 acc[2][2];
  #pragma unroll
  for (int mt = 0; mt < 2; ++mt) {
    acc[mt][0] = (floatx4){0.f, 0.f, 0.f, 0.f};
    acc[mt][1] = (floatx4){0.f, 0.f, 0.f, 0.f};
  }
  #pragma unroll
  for (int kc = 0; kc < 4; ++kc)
    #pragma unroll
    for (int mt = 0; mt < 2; ++mt) {
      const short8 afr = *(const short8*)&sA[(mt * 16 + c15) * KP + kc * 32 + q * 8];
      acc[mt][0] = __builtin_amdgcn_mfma_f32_16x16x32_bf16(afr, bfr[kc][0], acc[mt][0], 0, 0, 0);
      acc[mt][1] = __builtin_amdgcn_mfma_f32_16x16x32_bf16(afr, bfr[kc][1], acc[mt][1], 0, 0, 0);
    }
  __syncthreads();   // sA dead

  // D -> sD[32][132] (2-way banks, free)
  #pragma unroll
  for (int mt = 0; mt < 2; ++mt)
    #pragma unroll
    for (int nt = 0; nt < 2; ++nt) {
      const int col = (w * 2 + nt) * 16 + c15;
      #pragma unroll
      for (int r = 0; r < 4; ++r)
        sD[(mt * 16 + q * 4 + r) * 132 + col] = acc[mt][nt][r];
    }
  __syncthreads();

  // coalesced stores: thread -> (row = t>>3, 16-col segment = t&7)
  const int orow = t >> 3, seg = t & 7;
  const int grow = row0 + orow;
  if (g == 0) {
    #pragma unroll
    for (int i = 0; i < 2; ++i) {     // 8 cols per iter
      const float4 v0 = *(const float4*)&sD[orow * 132 + seg * 16 + i * 8];
      const float4 v1 = *(const float4*)&sD[orow * 132 + seg * 16 + i * 8 + 4];
      uint4 u;
      u.x = (unsigned)f2bf(v0.x) | ((unsigned)f2bf(v0.y) << 16);
      u.y = (unsigned)f2bf(v0.z) | ((unsigned)f2bf(v0.w) << 16);
      u.z = (unsigned)f2bf(v1.x) | ((unsigned)f2bf(v1.y) << 16);
      u.w = (unsigned)f2bf(v1.z) | ((unsigned)f2bf(v1.w) << 16);
      *(uint4*)&xh[(long)grow * 128 + seg * 16 + i * 8] = u;
    }
    // fused alpha epilogue: thread = (node orow, head seg); one 16-dot each.
    const int h = seg;
    float sl = 0.f, sr = 0.f;
    #pragma unroll
    for (int c4 = 0; c4 < 4; ++c4) {
      const float4 xv = *(const float4*)&sD[orow * 132 + h * 16 + c4 * 4];
      const float4 lv = *(const float4*)&attl[h * 16 + c4 * 4];
      const float4 rv = *(const float4*)&attr[h * 16 + c4 * 4];
      sl += xv.x * lv.x + xv.y * lv.y + xv.z * lv.z + xv.w * lv.w;
      sr += xv.x * rv.x + xv.y * rv.y + xv.z * rv.z + xv.w * rv.w;
    }
    al[(long)grow * 8 + h] = sl;
    ar[(long)grow * 8 + h] = sr;
  } else {
    #pragma unroll
    for (int i = 0; i < 4; ++i) {
      const float4 v = *(const float4*)&sD[orow * 132 + seg * 16 + i * 4];
      *(float4*)&outp[(long)grow * 128 + seg * 16 + i * 4] = v;
    }
  }
}

// Exclusive scan of 625 bucket totals (single block).
__global__ __launch_bounds__(1024) void k_scan_g(
    const int* __restrict__ gcnt, int* __restrict__ gbase)
{
  __shared__ int sd[1024];
  const int t = threadIdx.x;
  const int v = (t < NBUCK) ? gcnt[t] : 0;
  sd[t] = v;
  __syncthreads();
  #pragma unroll
  for (int off = 1; off < 1024; off <<= 1) {
    const int add = (t >= off) ? sd[t - off] : 0;
    __syncthreads();
    sd[t] += add;
    __syncthreads();
  }
  if (t < NBUCK) gbase[t] = sd[t] - v;
}

// Two-pass fill per 4000-edge chunk: (1) LDS bucket counts, (2) one reserve
// atomic per (block,bucket) (~100K total), (3) recompute + scatter into the
// block's contiguous per-bucket runs. No per-edge global atomics.
// pexp: no max subtraction (logits bounded ~|4|, softmax shift-invariant —
// validated in earlier rounds).
__global__ __launch_bounds__(512) void k_fill(
    const int* __restrict__ src, const int* __restrict__ dst,
    const float* __restrict__ ew, const float* __restrict__ al,
    const float* __restrict__ ar, const int* __restrict__ gbase,
    int* __restrict__ gcur,
    unsigned short* __restrict__ pexph, int* __restrict__ meta)
{
  __shared__ int lcnt[NBUCK];   // pass1 counts, reused as pass2 cursor
  __shared__ int lbase[NBUCK];
  const int t = threadIdx.x;
  for (int i = t; i < NBUCK; i += 512) lcnt[i] = 0;
  __syncthreads();
  const int e0 = blockIdx.x * ECH_F;
  for (int e = e0 + t; e < e0 + ECH_F; e += 512)
    atomicAdd(&lcnt[dst[e] >> 6], 1);
  __syncthreads();
  for (int i = t; i < NBUCK; i += 512) {
    const int c = lcnt[i];
    lbase[i] = c ? (gbase[i] + atomicAdd(&gcur[i], c)) : 0;
    lcnt[i] = 0;
  }
  __syncthreads();
  for (int e = e0 + t; e < e0 + ECH_F; e += 512) {
    const int s = src[e], d = dst[e];
    const float w = ew[e];
    const float4 l0 = *(const float4*)&al[(long)s * 8];
    const float4 l1 = *(const float4*)&al[(long)s * 8 + 4];
    const float4 r0 = *(const float4*)&ar[(long)d * 8];
    const float4 r1 = *(const float4*)&ar[(long)d * 8 + 4];
    float lv[8] = {l0.x + r0.x, l0.y + r0.y, l0.z + r0.z, l0.w + r0.w,
                   l1.x + r1.x, l1.y + r1.y, l1.z + r1.z, l1.w + r1.w};
    #pragma unroll
    for (int h = 0; h < 8; ++h) {
      float a = w * lv[h];
      a = (a >= 0.f) ? a : 0.2f * a;   // leaky_relu(0.2)
      lv[h] = __expf(a);
    }
    const int b = d >> 6;
    const int p = lbase[b] + atomicAdd(&lcnt[b], 1);   // LDS atomic only
    meta[p] = ((d & 63) << 16) | s;
    uint4 u;
    u.x = (unsigned)f2bf(lv[0]) | ((unsigned)f2bf(lv[1]) << 16);
    u.y = (unsigned)f2bf(lv[2]) | ((unsigned)f2bf(lv[3]) << 16);
    u.z = (unsigned)f2bf(lv[4]) | ((unsigned)f2bf(lv[5]) << 16);
    u.w = (unsigned)f2bf(lv[6]) | ((unsigned)f2bf(lv[7]) << 16);
    *(uint4*)&pexph[(long)p * 8] = u;
  }
}

// One block per bucket: stage bucket's meta+pexp in LDS, counting-sort by
// local dst IN PLACE (write sorted meta=src and pexph back to the same
// global range), emit per-node CSR starts. Zero global atomics.
__global__ __launch_bounds__(256) void k_sort(
    const int* __restrict__ gbase, const int* __restrict__ gcnt,
    int* __restrict__ meta, unsigned short* __restrict__ pexph,
    int* __restrict__ nodeS)
{
  __shared__ int sm_raw[MAXB];
  __shared__ uint4 sm_pex[MAXB];
  __shared__ int bcnt[64], bbase[64], bpos[64];
  const int b = blockIdx.x;
  const int start = gbase[b];
  const int cntb = gcnt[b];
  const int t = threadIdx.x;
  if (t < 64) bcnt[t] = 0;
  __syncthreads();
  for (int i = t; i < cntb; i += 256) {
    const int m = meta[start + i];
    sm_raw[i] = m;
    sm_pex[i] = *(const uint4*)&pexph[(long)(start + i) * 8];
    atomicAdd(&bcnt[m >> 16], 1);
  }
  __syncthreads();
  if (t < 64) {            // wave 0: inclusive shuffle scan of 64 bins
    const int v = bcnt[t];
    int incl = v;
    #pragma unroll
    for (int off = 1; off < 64; off <<= 1) {
      const int n = __shfl_up(incl, off, 64);
      if (t >= off) incl += n;
    }
    bbase[t] = incl - v;
    bpos[t] = 0;
    nodeS[(b << 6) + t] = start + incl - v;
  }
  if (b == 0 && t == 64) nodeS[N_NODES] = N_EDGES;
  __syncthreads();
  for (int i = t; i < cntb; i += 256) {
    const int m = sm_raw[i];
    const int dl = m >> 16;
    const int r = atomicAdd(&bpos[dl], 1);   // LDS atomic only
    const int q = start + bbase[dl] + r;
    meta[q] = m & 0xFFFF;                    // src id
    *(uint4*)&pexph[(long)q * 8] = sm_pex[i];
  }
}

// One wave per node, SINGLE pass: acc += pexp * x, ssum += pexp; normalize
// at the end. Round-1-proven structure (register accumulation, 40K waves).
__global__ __launch_bounds__(256) void k_node_agg(
    const int* __restrict__ nodeS, const int* __restrict__ psrc,
    const unsigned short* __restrict__ pexph,
    const unsigned short* __restrict__ xh, float* __restrict__ outp)
{
  const int wave = threadIdx.x >> 6;
  const int lane = threadIdx.x & 63;
  const int d = blockIdx.x * 4 + wave;
  const int start = nodeS[d];
  const int end = nodeS[d + 1];
  if (end <= start) return;   // out already holds residual; elu(0)=0

  const int h = lane >> 3;
  const int co = lane * 2;

  float2 a0 = {0.f, 0.f}, a1 = {0.f, 0.f}, a2 = {0.f, 0.f}, a3 = {0.f, 0.f};
  float s0s = 0.f, s1s = 0.f, s2s = 0.f, s3s = 0.f;
  int p = start;
  for (; p + 4 <= end; p += 4) {
    const int s0 = psrc[p + 0], s1 = psrc[p + 1];
    const int s2 = psrc[p + 2], s3 = psrc[p + 3];
    const float e0 = bf2f(pexph[(long)(p + 0) * 8 + h]);
    const float e1 = bf2f(pexph[(long)(p + 1) * 8 + h]);
    const float e2 = bf2f(pexph[(long)(p + 2) * 8 + h]);
    const float e3 = bf2f(pexph[(long)(p + 3) * 8 + h]);
    const unsigned v0 = *(const unsigned*)&xh[(long)s0 * 128 + co];
    const unsigned v1 = *(const unsigned*)&xh[(long)s1 * 128 + co];
    const unsigned v2 = *(const unsigned*)&xh[(long)s2 * 128 + co];
    const unsigned v3 = *(const unsigned*)&xh[(long)s3 * 128 + co];
    a0.x = fmaf(bflo(v0), e0, a0.x); a0.y = fmaf(bfhi(v0), e0, a0.y); s0s += e0;
    a1.x = fmaf(bflo(v1), e1, a1.x); a1.y = fmaf(bfhi(v1), e1, a1.y); s1s += e1;
    a2.x = fmaf(bflo(v2), e2, a2.x); a2.y = fmaf(bfhi(v2), e2, a2.y); s2s += e2;
    a3.x = fmaf(bflo(v3), e3, a3.x); a3.y = fmaf(bfhi(v3), e3, a3.y); s3s += e3;
  }
  for (; p < end; ++p) {
    const int s = psrc[p];
    const float e0 = bf2f(pexph[(long)p * 8 + h]);
    const unsigned v = *(const unsigned*)&xh[(long)s * 128 + co];
    a0.x = fmaf(bflo(v), e0, a0.x);
    a0.y = fmaf(bfhi(v), e0, a0.y);
    s0s += e0;
  }
  const float rs = 1.0f / ((s0s + s1s) + (s2s + s3s));
  const float ax = ((a0.x + a1.x) + (a2.x + a3.x)) * rs;
  const float ay = ((a0.y + a1.y) + (a2.y + a3.y)) * rs;

  float2 o = *(float2*)&outp[(long)d * 128 + co];
  o.x += (ax > 0.f) ? ax : expm1f(ax);
  o.y += (ay > 0.f) ? ay : expm1f(ay);
  *(float2*)&outp[(long)d * 128 + co] = o;
}

extern "C" void kernel_launch(void* const* d_in, const int* in_sizes, int n_in,
                              void* d_out, int out_size, void* d_ws, size_t ws_size,
                              hipStream_t stream) {
  const float* feat = (const float*)d_in[0];
  const int*   eidx = (const int*)d_in[1];
  const float* ew   = (const float*)d_in[2];
  const float* Wlin = (const float*)d_in[3];
  const float* attl = (const float*)d_in[4];
  const float* attr = (const float*)d_in[5];
  const float* Wres = (const float*)d_in[6];
  float* outp = (float*)d_out;

  float* ws = (float*)d_ws;
  unsigned short* xh = (unsigned short*)ws;
  float* al   = ws + 5120000;
  float* ar   = ws + 5440000;
  unsigned short* pexph = (unsigned short*)(ws + 5760000);
  int*   meta = (int*)(ws + 10880000);
  int*   gcnt = (int*)(ws + 11600000);
  int*   gcur = gcnt + NBUCK;            // adjacent: one memset
  int*   gbase = (int*)(ws + 11602000);
  int*   nodeS = (int*)(ws + 11700000);  // 40001 ints
  unsigned short* wt = (unsigned short*)(ws + 12800000);

  const int* src = eidx;
  const int* dst = eidx + N_EDGES;

  hipMemsetAsync(gcnt, 0, (size_t)2 * NBUCK * 4, stream);  // gcnt + gcur

  dim3 pgrid(128, 2);
  k_prep<<<pgrid, 128, 0, stream>>>(Wlin, Wres, wt);
  dim3 ggrid(NBG, 3);  // y=0 lin+alpha, y=1 res, y=2 bucket histogram
  k_gemm<<<ggrid, 256, 0, stream>>>(feat, wt, xh, outp, dst, gcnt,
                                    attl, attr, al, ar);
  k_scan_g<<<1, 1024, 0, stream>>>(gcnt, gbase);
  k_fill<<<NFILL, 512, 0, stream>>>(src, dst, ew, al, ar, gbase, gcur,
                                    pexph, meta);
  k_sort<<<NBUCK, 256, 0, stream>>>(gbase, gcnt, meta, pexph, nodeS);
  k_node_agg<<<N_NODES / 4, 256, 0, stream>>>(nodeS, meta, pexph, xh, outp);
}

// Round 4
// 183.634 us; speedup vs baseline: 3.8179x; 1.0444x over previous
//
#include <hip/hip_runtime.h>
#include <math.h>

#define N_NODES 40000
#define N_EDGES 640000
#define D 128
#define H 8
#define C 16
#define NBG 1250     // 40000/32 exactly
#define KP 136       // sA k-stride (bf16 elems)
#define NBUCK 625    // 64-node buckets: bucket = dst >> 6 (40000 = 625*64)
#define NCH 512      // count-matrix chunks
#define ECH 1250     // edges per chunk (512*1250 = 640000)
#define MAXB 1536    // bucket-size bound (mean 1024, sigma 32; 16-sigma guard)

typedef __attribute__((ext_vector_type(8))) short short8;   // 8 bf16 (4 VGPRs)
typedef __attribute__((ext_vector_type(4))) float floatx4;  // MFMA C/D

// ws layout (float offsets):
//  xh    : 0          .. 2,560,000   (N*128 bf16 stored as ushort)
//  al    : 5,120,000  .. 5,440,000   (N*8)
//  ar    : 5,440,000  .. 5,760,000   (N*8)
//  pexph : 5,760,000  .. 8,320,000   (E*8 bf16 ushort; bucket-grouped after
//                                     k_fill, node-sorted after k_sort)
//  rank  : 8,320,000  .. 8,960,000   (E ints, intra-(chunk,bucket) rank)
//  meta  : 10,880,000 .. 11,520,000  (E ints; (dlocal<<16)|src after k_fill,
//                                     src after k_sort)
//  cnt2  : 11,560,000 .. 11,880,000  ([512][625] ints)
//  pre2T : 11,880,000 .. 12,200,000  ([625][512] ints, transposed prefixes)
//  total : 12,200,000 .. +625        (per-bucket totals)
//  gbase : 12,210,000 .. +625        (per-bucket exclusive scan)
//  nodeS : 12,220,000 .. +40,001     (per-node CSR starts, from k_sort)
//  wt    : 12,800,000 .. +8,192 floats (2x 128x128 bf16 transposed weights)

__device__ __forceinline__ unsigned short f2bf(float f) {
  const unsigned u = __float_as_uint(f);
  return (unsigned short)((u + 0x7FFFu + ((u >> 16) & 1u)) >> 16);  // RNE
}
__device__ __forceinline__ float bflo(unsigned p) {
  return __uint_as_float(p << 16);
}
__device__ __forceinline__ float bfhi(unsigned p) {
  return __uint_as_float(p & 0xFFFF0000u);
}
__device__ __forceinline__ float bf2f(unsigned short u) {
  return __uint_as_float((unsigned)u << 16);
}

// Pre-transpose W (fp32 [k][n]) -> wt (bf16 [g][n][k]). 64 KB total.
__global__ void k_prep(const float* __restrict__ Wlin,
                       const float* __restrict__ Wres,
                       unsigned short* __restrict__ wt)
{
  const int n = blockIdx.x, k = threadIdx.x, g = blockIdx.y;
  const float* W = g ? Wres : Wlin;
  wt[((g * 128 + n) * 128) + k] = f2bf(W[(long)k * 128 + n]);
}

// MFMA bf16 GEMM, 32-row blocks, BOTH weight matrices per block (feat staged
// once; halves block count and removes a redundant 20 MB feat read).
// Epilogue: xh=bf16(feat@Wlin) + fused alpha_l/alpha_r, then outp=feat@Wres.
__global__ __launch_bounds__(256, 4) void k_gemm(
    const float* __restrict__ feat, const unsigned short* __restrict__ wt,
    unsigned short* __restrict__ xh, float* __restrict__ outp,
    const float* __restrict__ attl, const float* __restrict__ attr,
    float* __restrict__ al, float* __restrict__ ar)
{
  __shared__ short sA[32 * KP];     // 8,704 B
  __shared__ float sD[32 * 132];    // 16,896 B
  const int t = threadIdx.x;
  const int row0 = blockIdx.x * 32;

  // stage A: 32 rows x 128 k, fp32 -> bf16 (coalesced float4 reads)
  {
    const int kq = t & 31;            // k = kq*4
    const int rb = (t >> 5) * 4;      // 4 rows per thread
    #pragma unroll
    for (int i = 0; i < 4; ++i) {
      const int r = rb + i;
      const float4 f = *(const float4*)&feat[(long)(row0 + r) * 128 + kq * 4];
      const unsigned lo = (unsigned)f2bf(f.x) | ((unsigned)f2bf(f.y) << 16);
      const unsigned hi = (unsigned)f2bf(f.z) | ((unsigned)f2bf(f.w) << 16);
      *(uint2*)&sA[r * KP + kq * 4] = make_uint2(lo, hi);
    }
  }

  const int w = t >> 6, lane = t & 63;
  const int c15 = lane & 15, q = lane >> 4;

  // B frags for both weight matrices: wave w owns n-tiles {2w, 2w+1}
  short8 bfr0[4][2], bfr1[4][2];
  #pragma unroll
  for (int kc = 0; kc < 4; ++kc)
    #pragma unroll
    for (int nt = 0; nt < 2; ++nt) {
      const int n = (w * 2 + nt) * 16 + c15;
      bfr0[kc][nt] = *(const short8*)&wt[n * 128 + kc * 32 + q * 8];
      bfr1[kc][nt] = *(const short8*)&wt[16384 + n * 128 + kc * 32 + q * 8];
    }
  __syncthreads();

  floatx4 acc0[2][2], acc1[2][2];
  #pragma unroll
  for (int mt = 0; mt < 2; ++mt)
    #pragma unroll
    for (int nt = 0; nt < 2; ++nt) {
      acc0[mt][nt] = (floatx4){0.f, 0.f, 0.f, 0.f};
      acc1[mt][nt] = (floatx4){0.f, 0.f, 0.f, 0.f};
    }
  #pragma unroll
  for (int kc = 0; kc < 4; ++kc)
    #pragma unroll
    for (int mt = 0; mt < 2; ++mt) {
      const short8 afr = *(const short8*)&sA[(mt * 16 + c15) * KP + kc * 32 + q * 8];
      acc0[mt][0] = __builtin_amdgcn_mfma_f32_16x16x32_bf16(afr, bfr0[kc][0], acc0[mt][0], 0, 0, 0);
      acc0[mt][1] = __builtin_amdgcn_mfma_f32_16x16x32_bf16(afr, bfr0[kc][1], acc0[mt][1], 0, 0, 0);
      acc1[mt][0] = __builtin_amdgcn_mfma_f32_16x16x32_bf16(afr, bfr1[kc][0], acc1[mt][0], 0, 0, 0);
      acc1[mt][1] = __builtin_amdgcn_mfma_f32_16x16x32_bf16(afr, bfr1[kc][1], acc1[mt][1], 0, 0, 0);
    }

  const int orow = t >> 3, seg = t & 7;
  const int grow = row0 + orow;

  // ---- pass 0: xh + alpha from acc0 ----
  #pragma unroll
  for (int mt = 0; mt < 2; ++mt)
    #pragma unroll
    for (int nt = 0; nt < 2; ++nt) {
      const int col = (w * 2 + nt) * 16 + c15;
      #pragma unroll
      for (int r = 0; r < 4; ++r)
        sD[(mt * 16 + q * 4 + r) * 132 + col] = acc0[mt][nt][r];
    }
  __syncthreads();
  {
    #pragma unroll
    for (int i = 0; i < 2; ++i) {     // 8 cols per iter
      const float4 v0 = *(const float4*)&sD[orow * 132 + seg * 16 + i * 8];
      const float4 v1 = *(const float4*)&sD[orow * 132 + seg * 16 + i * 8 + 4];
      uint4 u;
      u.x = (unsigned)f2bf(v0.x) | ((unsigned)f2bf(v0.y) << 16);
      u.y = (unsigned)f2bf(v0.z) | ((unsigned)f2bf(v0.w) << 16);
      u.z = (unsigned)f2bf(v1.x) | ((unsigned)f2bf(v1.y) << 16);
      u.w = (unsigned)f2bf(v1.z) | ((unsigned)f2bf(v1.w) << 16);
      *(uint4*)&xh[(long)grow * 128 + seg * 16 + i * 8] = u;
    }
    // fused alpha epilogue: thread = (node orow, head seg); one 16-dot each.
    const int h = seg;
    float sl = 0.f, sr = 0.f;
    #pragma unroll
    for (int c4 = 0; c4 < 4; ++c4) {
      const float4 xv = *(const float4*)&sD[orow * 132 + h * 16 + c4 * 4];
      const float4 lv = *(const float4*)&attl[h * 16 + c4 * 4];
      const float4 rv = *(const float4*)&attr[h * 16 + c4 * 4];
      sl += xv.x * lv.x + xv.y * lv.y + xv.z * lv.z + xv.w * lv.w;
      sr += xv.x * rv.x + xv.y * rv.y + xv.z * rv.z + xv.w * rv.w;
    }
    al[(long)grow * 8 + h] = sl;
    ar[(long)grow * 8 + h] = sr;
  }
  __syncthreads();

  // ---- pass 1: outp from acc1 ----
  #pragma unroll
  for (int mt = 0; mt < 2; ++mt)
    #pragma unroll
    for (int nt = 0; nt < 2; ++nt) {
      const int col = (w * 2 + nt) * 16 + c15;
      #pragma unroll
      for (int r = 0; r < 4; ++r)
        sD[(mt * 16 + q * 4 + r) * 132 + col] = acc1[mt][nt][r];
    }
  __syncthreads();
  #pragma unroll
  for (int i = 0; i < 4; ++i) {
    const float4 v = *(const float4*)&sD[orow * 132 + seg * 16 + i * 4];
    *(float4*)&outp[(long)grow * 128 + seg * 16 + i * 4] = v;
  }
}

// Per-chunk bucket histogram + per-edge rank (LDS cursor). No global atomics.
__global__ __launch_bounds__(512) void k_cnt(
    const int* __restrict__ dst, int* __restrict__ rank, int* __restrict__ cnt2)
{
  __shared__ int lcnt[NBUCK];
  const int t = threadIdx.x;
  const int c = blockIdx.x;
  for (int i = t; i < NBUCK; i += 512) lcnt[i] = 0;
  __syncthreads();
  const int e0 = c * ECH;
  for (int e = e0 + t; e < e0 + ECH; e += 512)
    rank[e] = atomicAdd(&lcnt[dst[e] >> 6], 1);   // LDS atomic only
  __syncthreads();
  for (int i = t; i < NBUCK; i += 512) cnt2[c * NBUCK + i] = lcnt[i];
}

// Per-bucket scan over 512 chunk-counts -> pre2T[b][c] (coalesced) + total[b].
__global__ __launch_bounds__(512) void k_scan2a(
    const int* __restrict__ cnt2, int* __restrict__ pre2T, int* __restrict__ total)
{
  __shared__ int sd[NCH];
  const int b = blockIdx.x;
  const int t = threadIdx.x;
  const int v = cnt2[t * NBUCK + b];   // strided read (one per thread)
  sd[t] = v;
  __syncthreads();
  #pragma unroll
  for (int off = 1; off < NCH; off <<= 1) {
    const int add = (t >= off) ? sd[t - off] : 0;
    __syncthreads();
    sd[t] += add;
    __syncthreads();
  }
  pre2T[b * NCH + t] = sd[t] - v;
  if (t == NCH - 1) total[b] = sd[t];
}

// Exclusive scan of 625 bucket totals (single block).
__global__ __launch_bounds__(1024) void k_scan_g(
    const int* __restrict__ total, int* __restrict__ gbase)
{
  __shared__ int sd[1024];
  const int t = threadIdx.x;
  const int v = (t < NBUCK) ? total[t] : 0;
  sd[t] = v;
  __syncthreads();
  #pragma unroll
  for (int off = 1; off < 1024; off <<= 1) {
    const int add = (t >= off) ? sd[t - off] : 0;
    __syncthreads();
    sd[t] += add;
    __syncthreads();
  }
  if (t < NBUCK) gbase[t] = sd[t] - v;
}

// One thread per edge; slot fully precomputed (gbase + pre2T + rank): no
// atomics, no LDS, no barriers -> 10K waves hide the al/ar gathers and the
// scattered pexp/meta writes. pexp: no max subtraction (logits bounded ~|4|,
// softmax shift-invariant — validated in earlier rounds).
__global__ __launch_bounds__(256) void k_fill(
    const int* __restrict__ src, const int* __restrict__ dst,
    const float* __restrict__ ew, const float* __restrict__ al,
    const float* __restrict__ ar, const int* __restrict__ gbase,
    const int* __restrict__ pre2T, const int* __restrict__ rank,
    unsigned short* __restrict__ pexph, int* __restrict__ meta)
{
  const int e = blockIdx.x * 256 + threadIdx.x;
  if (e >= N_EDGES) return;
  const int s = src[e], d = dst[e];
  const float w = ew[e];
  const int b = d >> 6;
  const int c = e / ECH;
  const int p = gbase[b] + pre2T[b * NCH + c] + rank[e];
  const float4 l0 = *(const float4*)&al[(long)s * 8];
  const float4 l1 = *(const float4*)&al[(long)s * 8 + 4];
  const float4 r0 = *(const float4*)&ar[(long)d * 8];
  const float4 r1 = *(const float4*)&ar[(long)d * 8 + 4];
  float lv[8] = {l0.x + r0.x, l0.y + r0.y, l0.z + r0.z, l0.w + r0.w,
                 l1.x + r1.x, l1.y + r1.y, l1.z + r1.z, l1.w + r1.w};
  #pragma unroll
  for (int h = 0; h < 8; ++h) {
    float a = w * lv[h];
    a = (a >= 0.f) ? a : 0.2f * a;   // leaky_relu(0.2)
    lv[h] = __expf(a);
  }
  meta[p] = ((d & 63) << 16) | s;
  uint4 u;
  u.x = (unsigned)f2bf(lv[0]) | ((unsigned)f2bf(lv[1]) << 16);
  u.y = (unsigned)f2bf(lv[2]) | ((unsigned)f2bf(lv[3]) << 16);
  u.z = (unsigned)f2bf(lv[4]) | ((unsigned)f2bf(lv[5]) << 16);
  u.w = (unsigned)f2bf(lv[6]) | ((unsigned)f2bf(lv[7]) << 16);
  *(uint4*)&pexph[(long)p * 8] = u;
}

// One block per bucket: stage bucket's meta+pexp in LDS, counting-sort by
// local dst IN PLACE (write sorted meta=src and pexph back to the same
// global range), emit per-node CSR starts. Zero global atomics.
__global__ __launch_bounds__(256) void k_sort(
    const int* __restrict__ gbase, const int* __restrict__ total,
    int* __restrict__ meta, unsigned short* __restrict__ pexph,
    int* __restrict__ nodeS)
{
  __shared__ int sm_raw[MAXB];
  __shared__ uint4 sm_pex[MAXB];
  __shared__ int bcnt[64], bbase[64], bpos[64];
  const int b = blockIdx.x;
  const int start = gbase[b];
  const int cntb = total[b];
  const int t = threadIdx.x;
  if (t < 64) bcnt[t] = 0;
  __syncthreads();
  for (int i = t; i < cntb; i += 256) {
    const int m = meta[start + i];
    sm_raw[i] = m;
    sm_pex[i] = *(const uint4*)&pexph[(long)(start + i) * 8];
    atomicAdd(&bcnt[m >> 16], 1);
  }
  __syncthreads();
  if (t < 64) {            // wave 0: inclusive shuffle scan of 64 bins
    const int v = bcnt[t];
    int incl = v;
    #pragma unroll
    for (int off = 1; off < 64; off <<= 1) {
      const int n = __shfl_up(incl, off, 64);
      if (t >= off) incl += n;
    }
    bbase[t] = incl - v;
    bpos[t] = 0;
    nodeS[(b << 6) + t] = start + incl - v;
  }
  if (b == 0 && t == 64) nodeS[N_NODES] = N_EDGES;
  __syncthreads();
  for (int i = t; i < cntb; i += 256) {
    const int m = sm_raw[i];
    const int dl = m >> 16;
    const int r = atomicAdd(&bpos[dl], 1);   // LDS atomic only
    const int q = start + bbase[dl] + r;
    meta[q] = m & 0xFFFF;                    // src id
    *(uint4*)&pexph[(long)q * 8] = sm_pex[i];
  }
}

// One wave per node, SINGLE pass: acc += pexp * x, ssum += pexp; normalize
// at the end. Round-1-proven structure (register accumulation, 40K waves).
__global__ __launch_bounds__(256) void k_node_agg(
    const int* __restrict__ nodeS, const int* __restrict__ psrc,
    const unsigned short* __restrict__ pexph,
    const unsigned short* __restrict__ xh, float* __restrict__ outp)
{
  const int wave = threadIdx.x >> 6;
  const int lane = threadIdx.x & 63;
  const int d = blockIdx.x * 4 + wave;
  const int start = nodeS[d];
  const int end = nodeS[d + 1];
  if (end <= start) return;   // out already holds residual; elu(0)=0

  const int h = lane >> 3;
  const int co = lane * 2;

  float2 a0 = {0.f, 0.f}, a1 = {0.f, 0.f}, a2 = {0.f, 0.f}, a3 = {0.f, 0.f};
  float s0s = 0.f, s1s = 0.f, s2s = 0.f, s3s = 0.f;
  int p = start;
  for (; p + 4 <= end; p += 4) {
    const int s0 = psrc[p + 0], s1 = psrc[p + 1];
    const int s2 = psrc[p + 2], s3 = psrc[p + 3];
    const float e0 = bf2f(pexph[(long)(p + 0) * 8 + h]);
    const float e1 = bf2f(pexph[(long)(p + 1) * 8 + h]);
    const float e2 = bf2f(pexph[(long)(p + 2) * 8 + h]);
    const float e3 = bf2f(pexph[(long)(p + 3) * 8 + h]);
    const unsigned v0 = *(const unsigned*)&xh[(long)s0 * 128 + co];
    const unsigned v1 = *(const unsigned*)&xh[(long)s1 * 128 + co];
    const unsigned v2 = *(const unsigned*)&xh[(long)s2 * 128 + co];
    const unsigned v3 = *(const unsigned*)&xh[(long)s3 * 128 + co];
    a0.x = fmaf(bflo(v0), e0, a0.x); a0.y = fmaf(bfhi(v0), e0, a0.y); s0s += e0;
    a1.x = fmaf(bflo(v1), e1, a1.x); a1.y = fmaf(bfhi(v1), e1, a1.y); s1s += e1;
    a2.x = fmaf(bflo(v2), e2, a2.x); a2.y = fmaf(bfhi(v2), e2, a2.y); s2s += e2;
    a3.x = fmaf(bflo(v3), e3, a3.x); a3.y = fmaf(bfhi(v3), e3, a3.y); s3s += e3;
  }
  for (; p < end; ++p) {
    const int s = psrc[p];
    const float e0 = bf2f(pexph[(long)p * 8 + h]);
    const unsigned v = *(const unsigned*)&xh[(long)s * 128 + co];
    a0.x = fmaf(bflo(v), e0, a0.x);
    a0.y = fmaf(bfhi(v), e0, a0.y);
    s0s += e0;
  }
  const float rs = 1.0f / ((s0s + s1s) + (s2s + s3s));
  const float ax = ((a0.x + a1.x) + (a2.x + a3.x)) * rs;
  const float ay = ((a0.y + a1.y) + (a2.y + a3.y)) * rs;

  float2 o = *(float2*)&outp[(long)d * 128 + co];
  o.x += (ax > 0.f) ? ax : expm1f(ax);
  o.y += (ay > 0.f) ? ay : expm1f(ay);
  *(float2*)&outp[(long)d * 128 + co] = o;
}

extern "C" void kernel_launch(void* const* d_in, const int* in_sizes, int n_in,
                              void* d_out, int out_size, void* d_ws, size_t ws_size,
                              hipStream_t stream) {
  const float* feat = (const float*)d_in[0];
  const int*   eidx = (const int*)d_in[1];
  const float* ew   = (const float*)d_in[2];
  const float* Wlin = (const float*)d_in[3];
  const float* attl = (const float*)d_in[4];
  const float* attr = (const float*)d_in[5];
  const float* Wres = (const float*)d_in[6];
  float* outp = (float*)d_out;

  float* ws = (float*)d_ws;
  unsigned short* xh = (unsigned short*)ws;
  float* al   = ws + 5120000;
  float* ar   = ws + 5440000;
  unsigned short* pexph = (unsigned short*)(ws + 5760000);
  int*   rank = (int*)(ws + 8320000);
  int*   meta = (int*)(ws + 10880000);
  int*   cnt2 = (int*)(ws + 11560000);
  int*   pre2T = (int*)(ws + 11880000);
  int*   total = (int*)(ws + 12200000);
  int*   gbase = (int*)(ws + 12210000);
  int*   nodeS = (int*)(ws + 12220000);  // 40001 ints
  unsigned short* wt = (unsigned short*)(ws + 12800000);

  const int* src = eidx;
  const int* dst = eidx + N_EDGES;

  dim3 pgrid(128, 2);
  k_prep<<<pgrid, 128, 0, stream>>>(Wlin, Wres, wt);
  k_gemm<<<NBG, 256, 0, stream>>>(feat, wt, xh, outp, attl, attr, al, ar);
  k_cnt<<<NCH, 512, 0, stream>>>(dst, rank, cnt2);
  k_scan2a<<<NBUCK, NCH, 0, stream>>>(cnt2, pre2T, total);
  k_scan_g<<<1, 1024, 0, stream>>>(total, gbase);
  k_fill<<<(N_EDGES + 255) / 256, 256, 0, stream>>>(src, dst, ew, al, ar,
                                                    gbase, pre2T, rank,
                                                    pexph, meta);
  k_sort<<<NBUCK, 256, 0, stream>>>(gbase, total, meta, pexph, nodeS);
  k_node_agg<<<N_NODES / 4, 256, 0, stream>>>(nodeS, meta, pexph, xh, outp);
}

// Round 5
// 163.958 us; speedup vs baseline: 4.2761x; 1.1200x over previous
//
#include <hip/hip_runtime.h>
#include <math.h>

#define N_NODES 40000
#define N_EDGES 640000
#define D 128
#define H 8
#define C 16
#define NBG 1250     // 40000/32 exactly
#define KP 136       // sA k-stride (bf16 elems)
#define NBUCK 625    // 64-node buckets: bucket = dst >> 6 (40000 = 625*64)
#define NCH 512      // count-matrix chunks
#define ECH 1250     // edges per chunk (512*1250 = 640000)
#define MAXB 1536    // bucket-size bound (mean 1024, sigma 32; 16-sigma guard)

typedef __attribute__((ext_vector_type(8))) short short8;   // 8 bf16 (4 VGPRs)
typedef __attribute__((ext_vector_type(4))) float floatx4;  // MFMA C/D

// ws layout (float offsets):
//  xh    : 0          .. 2,560,000   (N*128 bf16 stored as ushort)
//  al    : 5,120,000  .. 5,440,000   (N*8)
//  ar    : 5,440,000  .. 5,760,000   (N*8)
//  pexph : 5,760,000  .. 8,320,000   (E*8 bf16 ushort, node-sorted, written
//                                     ONCE coalesced by k_edge)
//  pk    : 8,320,000  .. 8,960,000   (E ints, (b<<17)|(dl<<11)|rank)
//  einfo : 9,000,000  .. 10,280,000  (E uint2, bucket-grouped (src<<6)|dl, ew)
//  psrc  : 10,880,000 .. 11,520,000  (E ints, node-sorted src ids)
//  cnt2  : 11,560,000 .. 11,880,000  ([512][625] ints)
//  pre2T : 11,880,000 .. 12,200,000  ([625][512] ints, transposed prefixes)
//  total : 12,200,000 .. +625        (per-bucket totals)
//  gbase : 12,210,000 .. +625        (per-bucket exclusive scan)
//  nodeS : 12,220,000 .. +40,001     (per-node CSR starts, from k_edge)
//  wt    : 12,800,000 .. +8,192 floats (2x 128x128 bf16 transposed weights)

__device__ __forceinline__ unsigned short f2bf(float f) {
  const unsigned u = __float_as_uint(f);
  return (unsigned short)((u + 0x7FFFu + ((u >> 16) & 1u)) >> 16);  // RNE
}
__device__ __forceinline__ float bflo(unsigned p) {
  return __uint_as_float(p << 16);
}
__device__ __forceinline__ float bfhi(unsigned p) {
  return __uint_as_float(p & 0xFFFF0000u);
}
__device__ __forceinline__ float bf2f(unsigned short u) {
  return __uint_as_float((unsigned)u << 16);
}

// Pre-transpose W (fp32 [k][n]) -> wt (bf16 [g][n][k]). 64 KB total.
__global__ void k_prep(const float* __restrict__ Wlin,
                       const float* __restrict__ Wres,
                       unsigned short* __restrict__ wt)
{
  const int n = blockIdx.x, k = threadIdx.x, g = blockIdx.y;
  const float* W = g ? Wres : Wlin;
  wt[((g * 128 + n) * 128) + k] = f2bf(W[(long)k * 128 + n]);
}

// MFMA bf16 GEMM, 32-row blocks, BOTH weight matrices per block.
// blockIdx.y==0: xh=bf16(feat@Wlin) + fused alpha epilogue, outp=feat@Wres.
// blockIdx.y==1: per-chunk bucket histogram + packed per-edge rank word
//   pk[e]=(b<<17)|(dl<<11)|rank  (rank<2048, b<1024, dl<64). LDS atomics only;
//   overlaps the GEMM blocks' latency stalls, saves a launch boundary.
__global__ __launch_bounds__(256, 4) void k_gemm(
    const float* __restrict__ feat, const unsigned short* __restrict__ wt,
    unsigned short* __restrict__ xh, float* __restrict__ outp,
    const float* __restrict__ attl, const float* __restrict__ attr,
    float* __restrict__ al, float* __restrict__ ar,
    const int* __restrict__ dst, int* __restrict__ pk, int* __restrict__ cnt2)
{
  __shared__ short sA[32 * KP];     // 8,704 B
  __shared__ float sD[32 * 132];    // 16,896 B
  const int t = threadIdx.x;

  if (blockIdx.y == 1) {            // fused count/rank pass
    if (blockIdx.x >= NCH) return;
    int* lcnt = (int*)sA;           // 2,500 B
    for (int i = t; i < NBUCK; i += 256) lcnt[i] = 0;
    __syncthreads();
    const int c = blockIdx.x, e0 = c * ECH;
    for (int e = e0 + t; e < e0 + ECH; e += 256) {
      const int d = dst[e];
      const int r = atomicAdd(&lcnt[d >> 6], 1);   // LDS atomic only
      pk[e] = ((d >> 6) << 17) | ((d & 63) << 11) | r;
    }
    __syncthreads();
    for (int i = t; i < NBUCK; i += 256) cnt2[c * NBUCK + i] = lcnt[i];
    return;
  }

  const int row0 = blockIdx.x * 32;

  // stage A: 32 rows x 128 k, fp32 -> bf16 (coalesced float4 reads)
  {
    const int kq = t & 31;            // k = kq*4
    const int rb = (t >> 5) * 4;      // 4 rows per thread
    #pragma unroll
    for (int i = 0; i < 4; ++i) {
      const int r = rb + i;
      const float4 f = *(const float4*)&feat[(long)(row0 + r) * 128 + kq * 4];
      const unsigned lo = (unsigned)f2bf(f.x) | ((unsigned)f2bf(f.y) << 16);
      const unsigned hi = (unsigned)f2bf(f.z) | ((unsigned)f2bf(f.w) << 16);
      *(uint2*)&sA[r * KP + kq * 4] = make_uint2(lo, hi);
    }
  }

  const int w = t >> 6, lane = t & 63;
  const int c15 = lane & 15, q = lane >> 4;

  // B frags for both weight matrices: wave w owns n-tiles {2w, 2w+1}
  short8 bfr0[4][2], bfr1[4][2];
  #pragma unroll
  for (int kc = 0; kc < 4; ++kc)
    #pragma unroll
    for (int nt = 0; nt < 2; ++nt) {
      const int n = (w * 2 + nt) * 16 + c15;
      bfr0[kc][nt] = *(const short8*)&wt[n * 128 + kc * 32 + q * 8];
      bfr1[kc][nt] = *(const short8*)&wt[16384 + n * 128 + kc * 32 + q * 8];
    }
  __syncthreads();

  floatx4 acc0[2][2], acc1[2][2];
  #pragma unroll
  for (int mt = 0; mt < 2; ++mt)
    #pragma unroll
    for (int nt = 0; nt < 2; ++nt) {
      acc0[mt][nt] = (floatx4){0.f, 0.f, 0.f, 0.f};
      acc1[mt][nt] = (floatx4){0.f, 0.f, 0.f, 0.f};
    }
  #pragma unroll
  for (int kc = 0; kc < 4; ++kc)
    #pragma unroll
    for (int mt = 0; mt < 2; ++mt) {
      const short8 afr = *(const short8*)&sA[(mt * 16 + c15) * KP + kc * 32 + q * 8];
      acc0[mt][0] = __builtin_amdgcn_mfma_f32_16x16x32_bf16(afr, bfr0[kc][0], acc0[mt][0], 0, 0, 0);
      acc0[mt][1] = __builtin_amdgcn_mfma_f32_16x16x32_bf16(afr, bfr0[kc][1], acc0[mt][1], 0, 0, 0);
      acc1[mt][0] = __builtin_amdgcn_mfma_f32_16x16x32_bf16(afr, bfr1[kc][0], acc1[mt][0], 0, 0, 0);
      acc1[mt][1] = __builtin_amdgcn_mfma_f32_16x16x32_bf16(afr, bfr1[kc][1], acc1[mt][1], 0, 0, 0);
    }

  const int orow = t >> 3, seg = t & 7;
  const int grow = row0 + orow;

  // ---- pass 0: xh + alpha from acc0 ----
  #pragma unroll
  for (int mt = 0; mt < 2; ++mt)
    #pragma unroll
    for (int nt = 0; nt < 2; ++nt) {
      const int col = (w * 2 + nt) * 16 + c15;
      #pragma unroll
      for (int r = 0; r < 4; ++r)
        sD[(mt * 16 + q * 4 + r) * 132 + col] = acc0[mt][nt][r];
    }
  __syncthreads();
  {
    #pragma unroll
    for (int i = 0; i < 2; ++i) {     // 8 cols per iter
      const float4 v0 = *(const float4*)&sD[orow * 132 + seg * 16 + i * 8];
      const float4 v1 = *(const float4*)&sD[orow * 132 + seg * 16 + i * 8 + 4];
      uint4 u;
      u.x = (unsigned)f2bf(v0.x) | ((unsigned)f2bf(v0.y) << 16);
      u.y = (unsigned)f2bf(v0.z) | ((unsigned)f2bf(v0.w) << 16);
      u.z = (unsigned)f2bf(v1.x) | ((unsigned)f2bf(v1.y) << 16);
      u.w = (unsigned)f2bf(v1.z) | ((unsigned)f2bf(v1.w) << 16);
      *(uint4*)&xh[(long)grow * 128 + seg * 16 + i * 8] = u;
    }
    // fused alpha epilogue: thread = (node orow, head seg); one 16-dot each.
    const int h = seg;
    float sl = 0.f, sr = 0.f;
    #pragma unroll
    for (int c4 = 0; c4 < 4; ++c4) {
      const float4 xv = *(const float4*)&sD[orow * 132 + h * 16 + c4 * 4];
      const float4 lv = *(const float4*)&attl[h * 16 + c4 * 4];
      const float4 rv = *(const float4*)&attr[h * 16 + c4 * 4];
      sl += xv.x * lv.x + xv.y * lv.y + xv.z * lv.z + xv.w * lv.w;
      sr += xv.x * rv.x + xv.y * rv.y + xv.z * rv.z + xv.w * rv.w;
    }
    al[(long)grow * 8 + h] = sl;
    ar[(long)grow * 8 + h] = sr;
  }
  __syncthreads();

  // ---- pass 1: outp from acc1 ----
  #pragma unroll
  for (int mt = 0; mt < 2; ++mt)
    #pragma unroll
    for (int nt = 0; nt < 2; ++nt) {
      const int col = (w * 2 + nt) * 16 + c15;
      #pragma unroll
      for (int r = 0; r < 4; ++r)
        sD[(mt * 16 + q * 4 + r) * 132 + col] = acc1[mt][nt][r];
    }
  __syncthreads();
  #pragma unroll
  for (int i = 0; i < 4; ++i) {
    const float4 v = *(const float4*)&sD[orow * 132 + seg * 16 + i * 4];
    *(float4*)&outp[(long)grow * 128 + seg * 16 + i * 4] = v;
  }
}

// Per-bucket scan over 512 chunk-counts -> pre2T[b][c] (coalesced) + total[b].
__global__ __launch_bounds__(512) void k_scan2a(
    const int* __restrict__ cnt2, int* __restrict__ pre2T, int* __restrict__ total)
{
  __shared__ int sd[NCH];
  const int b = blockIdx.x;
  const int t = threadIdx.x;
  const int v = cnt2[t * NBUCK + b];   // strided read (one per thread)
  sd[t] = v;
  __syncthreads();
  #pragma unroll
  for (int off = 1; off < NCH; off <<= 1) {
    const int add = (t >= off) ? sd[t - off] : 0;
    __syncthreads();
    sd[t] += add;
    __syncthreads();
  }
  pre2T[b * NCH + t] = sd[t] - v;
  if (t == NCH - 1) total[b] = sd[t];
}

// Exclusive scan of 625 bucket totals (single block).
__global__ __launch_bounds__(1024) void k_scan_g(
    const int* __restrict__ total, int* __restrict__ gbase)
{
  __shared__ int sd[1024];
  const int t = threadIdx.x;
  const int v = (t < NBUCK) ? total[t] : 0;
  sd[t] = v;
  __syncthreads();
  #pragma unroll
  for (int off = 1; off < 1024; off <<= 1) {
    const int add = (t >= off) ? sd[t - off] : 0;
    __syncthreads();
    sd[t] += add;
    __syncthreads();
  }
  if (t < NBUCK) gbase[t] = sd[t] - v;
}

// One thread per edge: slot fully precomputed, single 8-byte scatter
// einfo[p] = {(src<<6)|dl, ew}. The ONLY scattered write in the pipeline.
__global__ __launch_bounds__(256) void k_place(
    const int* __restrict__ pk, const int* __restrict__ src,
    const float* __restrict__ ew, const int* __restrict__ gbase,
    const int* __restrict__ pre2T, uint2* __restrict__ einfo)
{
  const int e = blockIdx.x * 256 + threadIdx.x;
  if (e >= N_EDGES) return;
  const int k = pk[e];
  const int b = k >> 17, dl = (k >> 11) & 63, r = k & 2047;
  const int c = e / ECH;
  const int p = gbase[b] + pre2T[b * NCH + c] + r;
  einfo[p] = make_uint2(((unsigned)src[e] << 6) | (unsigned)dl,
                        __float_as_uint(ew[e]));
}

// One block per bucket: coalesced einfo read; ar for the bucket's 64 nodes
// staged in LDS; al gathered (L2-hot 1.28 MB); exp computed HERE; counting-
// sort by local dst in LDS; pexph/psrc written ONCE, coalesced, node-sorted.
// Emits per-node CSR starts. pexp: no max subtraction (logits bounded ~|4|,
// softmax shift-invariant — validated in earlier rounds).
__global__ __launch_bounds__(256) void k_edge(
    const int* __restrict__ gbase, const int* __restrict__ total,
    const uint2* __restrict__ einfo, const float* __restrict__ al,
    const float* __restrict__ ar,
    unsigned short* __restrict__ pexph, int* __restrict__ psrc,
    int* __restrict__ nodeS)
{
  __shared__ uint2 sE[MAXB];      // 12,288 B
  __shared__ float sAr[512];      //  2,048 B
  __shared__ int bcnt[64], bbase[64], bpos[64];
  const int b = blockIdx.x;
  const int start = gbase[b];
  const int cntb = total[b];
  const int t = threadIdx.x;
  if (t < 64) bcnt[t] = 0;
  for (int i = t; i < 512; i += 256) sAr[i] = ar[((long)b << 6) * 8 + i];
  __syncthreads();
  for (int i = t; i < cntb; i += 256) {
    const uint2 m = einfo[start + i];
    sE[i] = m;
    atomicAdd(&bcnt[m.x & 63], 1);   // LDS atomic only
  }
  __syncthreads();
  if (t < 64) {            // wave 0: inclusive shuffle scan of 64 bins
    const int v = bcnt[t];
    int incl = v;
    #pragma unroll
    for (int off = 1; off < 64; off <<= 1) {
      const int n = __shfl_up(incl, off, 64);
      if (t >= off) incl += n;
    }
    bbase[t] = incl - v;
    bpos[t] = 0;
    nodeS[(b << 6) + t] = start + incl - v;
  }
  if (b == 0 && t == 64) nodeS[N_NODES] = N_EDGES;
  __syncthreads();
  for (int i = t; i < cntb; i += 256) {
    const uint2 m = sE[i];
    const int dl = m.x & 63;
    const int s = (int)(m.x >> 6);
    const float w = __uint_as_float(m.y);
    const float4 l0 = *(const float4*)&al[(long)s * 8];
    const float4 l1 = *(const float4*)&al[(long)s * 8 + 4];
    const float* arr = &sAr[dl * 8];
    float lv[8] = {l0.x + arr[0], l0.y + arr[1], l0.z + arr[2], l0.w + arr[3],
                   l1.x + arr[4], l1.y + arr[5], l1.z + arr[6], l1.w + arr[7]};
    #pragma unroll
    for (int h = 0; h < 8; ++h) {
      float a = w * lv[h];
      a = (a >= 0.f) ? a : 0.2f * a;   // leaky_relu(0.2)
      lv[h] = __expf(a);
    }
    const int r = atomicAdd(&bpos[dl], 1);   // LDS atomic only
    const int q = start + bbase[dl] + r;
    psrc[q] = s;
    uint4 u;
    u.x = (unsigned)f2bf(lv[0]) | ((unsigned)f2bf(lv[1]) << 16);
    u.y = (unsigned)f2bf(lv[2]) | ((unsigned)f2bf(lv[3]) << 16);
    u.z = (unsigned)f2bf(lv[4]) | ((unsigned)f2bf(lv[5]) << 16);
    u.w = (unsigned)f2bf(lv[6]) | ((unsigned)f2bf(lv[7]) << 16);
    *(uint4*)&pexph[(long)q * 8] = u;
  }
}

// One wave per node, SINGLE pass: acc += pexp * x, ssum += pexp; normalize
// at the end. Round-1-proven structure (register accumulation, 40K waves).
__global__ __launch_bounds__(256) void k_node_agg(
    const int* __restrict__ nodeS, const int* __restrict__ psrc,
    const unsigned short* __restrict__ pexph,
    const unsigned short* __restrict__ xh, float* __restrict__ outp)
{
  const int wave = threadIdx.x >> 6;
  const int lane = threadIdx.x & 63;
  const int d = blockIdx.x * 4 + wave;
  const int start = nodeS[d];
  const int end = nodeS[d + 1];
  if (end <= start) return;   // out already holds residual; elu(0)=0

  const int h = lane >> 3;
  const int co = lane * 2;

  float2 a0 = {0.f, 0.f}, a1 = {0.f, 0.f}, a2 = {0.f, 0.f}, a3 = {0.f, 0.f};
  float s0s = 0.f, s1s = 0.f, s2s = 0.f, s3s = 0.f;
  int p = start;
  for (; p + 4 <= end; p += 4) {
    const int s0 = psrc[p + 0], s1 = psrc[p + 1];
    const int s2 = psrc[p + 2], s3 = psrc[p + 3];
    const float e0 = bf2f(pexph[(long)(p + 0) * 8 + h]);
    const float e1 = bf2f(pexph[(long)(p + 1) * 8 + h]);
    const float e2 = bf2f(pexph[(long)(p + 2) * 8 + h]);
    const float e3 = bf2f(pexph[(long)(p + 3) * 8 + h]);
    const unsigned v0 = *(const unsigned*)&xh[(long)s0 * 128 + co];
    const unsigned v1 = *(const unsigned*)&xh[(long)s1 * 128 + co];
    const unsigned v2 = *(const unsigned*)&xh[(long)s2 * 128 + co];
    const unsigned v3 = *(const unsigned*)&xh[(long)s3 * 128 + co];
    a0.x = fmaf(bflo(v0), e0, a0.x); a0.y = fmaf(bfhi(v0), e0, a0.y); s0s += e0;
    a1.x = fmaf(bflo(v1), e1, a1.x); a1.y = fmaf(bfhi(v1), e1, a1.y); s1s += e1;
    a2.x = fmaf(bflo(v2), e2, a2.x); a2.y = fmaf(bfhi(v2), e2, a2.y); s2s += e2;
    a3.x = fmaf(bflo(v3), e3, a3.x); a3.y = fmaf(bfhi(v3), e3, a3.y); s3s += e3;
  }
  for (; p < end; ++p) {
    const int s = psrc[p];
    const float e0 = bf2f(pexph[(long)p * 8 + h]);
    const unsigned v = *(const unsigned*)&xh[(long)s * 128 + co];
    a0.x = fmaf(bflo(v), e0, a0.x);
    a0.y = fmaf(bfhi(v), e0, a0.y);
    s0s += e0;
  }
  const float rs = 1.0f / ((s0s + s1s) + (s2s + s3s));
  const float ax = ((a0.x + a1.x) + (a2.x + a3.x)) * rs;
  const float ay = ((a0.y + a1.y) + (a2.y + a3.y)) * rs;

  float2 o = *(float2*)&outp[(long)d * 128 + co];
  o.x += (ax > 0.f) ? ax : expm1f(ax);
  o.y += (ay > 0.f) ? ay : expm1f(ay);
  *(float2*)&outp[(long)d * 128 + co] = o;
}

extern "C" void kernel_launch(void* const* d_in, const int* in_sizes, int n_in,
                              void* d_out, int out_size, void* d_ws, size_t ws_size,
                              hipStream_t stream) {
  const float* feat = (const float*)d_in[0];
  const int*   eidx = (const int*)d_in[1];
  const float* ew   = (const float*)d_in[2];
  const float* Wlin = (const float*)d_in[3];
  const float* attl = (const float*)d_in[4];
  const float* attr = (const float*)d_in[5];
  const float* Wres = (const float*)d_in[6];
  float* outp = (float*)d_out;

  float* ws = (float*)d_ws;
  unsigned short* xh = (unsigned short*)ws;
  float* al   = ws + 5120000;
  float* ar   = ws + 5440000;
  unsigned short* pexph = (unsigned short*)(ws + 5760000);
  int*   pk   = (int*)(ws + 8320000);
  uint2* einfo = (uint2*)(ws + 9000000);
  int*   psrc = (int*)(ws + 10880000);
  int*   cnt2 = (int*)(ws + 11560000);
  int*   pre2T = (int*)(ws + 11880000);
  int*   total = (int*)(ws + 12200000);
  int*   gbase = (int*)(ws + 12210000);
  int*   nodeS = (int*)(ws + 12220000);  // 40001 ints
  unsigned short* wt = (unsigned short*)(ws + 12800000);

  const int* src = eidx;
  const int* dst = eidx + N_EDGES;

  dim3 pgrid(128, 2);
  k_prep<<<pgrid, 128, 0, stream>>>(Wlin, Wres, wt);
  dim3 ggrid(NBG, 2);   // y=0 dual GEMM + alpha, y=1 count/rank
  k_gemm<<<ggrid, 256, 0, stream>>>(feat, wt, xh, outp, attl, attr, al, ar,
                                    dst, pk, cnt2);
  k_scan2a<<<NBUCK, NCH, 0, stream>>>(cnt2, pre2T, total);
  k_scan_g<<<1, 1024, 0, stream>>>(total, gbase);
  k_place<<<(N_EDGES + 255) / 256, 256, 0, stream>>>(pk, src, ew, gbase,
                                                     pre2T, einfo);
  k_edge<<<NBUCK, 256, 0, stream>>>(gbase, total, einfo, al, ar,
                                    pexph, psrc, nodeS);
  k_node_agg<<<N_NODES / 4, 256, 0, stream>>>(nodeS, psrc, pexph, xh, outp);
}

// Round 6
// 157.043 us; speedup vs baseline: 4.4644x; 1.0440x over previous
//
#include <hip/hip_runtime.h>
#include <math.h>

#define N_NODES 40000
#define N_EDGES 640000
#define D 128
#define H 8
#define C 16
#define NBG 1250     // 40000/32 exactly
#define KP 136       // sA k-stride (bf16 elems)
#define NBUCK 625    // 64-node buckets: bucket = dst >> 6 (40000 = 625*64)
#define NCH 512      // count-matrix chunks
#define ECH 1250     // edges per chunk (512*1250 = 640000)
#define MAXB 1536    // fixed bucket capacity (mean 1024, sigma~32; 16-sigma)

typedef __attribute__((ext_vector_type(8))) short short8;   // 8 bf16 (4 VGPRs)
typedef __attribute__((ext_vector_type(4))) float floatx4;  // MFMA C/D

// ws layout (float offsets):
//  xh    : 0         .. 2,560,000  (N*128 bf16 stored as ushort)
//  al    : 5,120,000 .. 5,440,000  (N*8)
//  ar    : 5,440,000 .. 5,760,000  (N*8)
//  pk    : 5,760,000 .. 6,400,000  (E ints, (b<<17)|(dl<<11)|rank)
//  einfo : 6,500,000 .. 8,420,000  (NBUCK*MAXB uint2, fixed-capacity bucket
//                                   slots; einfo[p]={(src<<6)|dl, ew})
//  cnt2  : 8,500,000 .. 8,820,000  ([512][625] ints)
//  pre2T : 8,900,000 .. 9,220,000  ([625][512] ints, transposed prefixes)
//  total : 9,300,000 .. +625       (per-bucket totals)
//  wt    : 12,800,000 .. +8,192 floats (2x 128x128 bf16 transposed weights)

__device__ __forceinline__ unsigned short f2bf(float f) {
  const unsigned u = __float_as_uint(f);
  return (unsigned short)((u + 0x7FFFu + ((u >> 16) & 1u)) >> 16);  // RNE
}
__device__ __forceinline__ float bflo(unsigned p) {
  return __uint_as_float(p << 16);
}
__device__ __forceinline__ float bfhi(unsigned p) {
  return __uint_as_float(p & 0xFFFF0000u);
}
__device__ __forceinline__ float bf2f(unsigned short u) {
  return __uint_as_float((unsigned)u << 16);
}

// Pre-transpose W (fp32 [k][n]) -> wt (bf16 [g][n][k]). 64 KB total.
__global__ void k_prep(const float* __restrict__ Wlin,
                       const float* __restrict__ Wres,
                       unsigned short* __restrict__ wt)
{
  const int n = blockIdx.x, k = threadIdx.x, g = blockIdx.y;
  const float* W = g ? Wres : Wlin;
  wt[((g * 128 + n) * 128) + k] = f2bf(W[(long)k * 128 + n]);
}

// MFMA bf16 GEMM, 32-row blocks, BOTH weight matrices per block.
// blockIdx.y==0: xh=bf16(feat@Wlin) + fused alpha epilogue, outp=feat@Wres.
// blockIdx.y==1: per-chunk bucket histogram + packed per-edge rank word
//   pk[e]=(b<<17)|(dl<<11)|rank. LDS atomics only; overlaps GEMM stalls.
__global__ __launch_bounds__(256, 4) void k_gemm(
    const float* __restrict__ feat, const unsigned short* __restrict__ wt,
    unsigned short* __restrict__ xh, float* __restrict__ outp,
    const float* __restrict__ attl, const float* __restrict__ attr,
    float* __restrict__ al, float* __restrict__ ar,
    const int* __restrict__ dst, int* __restrict__ pk, int* __restrict__ cnt2)
{
  __shared__ short sA[32 * KP];     // 8,704 B
  __shared__ float sD[32 * 132];    // 16,896 B
  const int t = threadIdx.x;

  if (blockIdx.y == 1) {            // fused count/rank pass
    if (blockIdx.x >= NCH) return;
    int* lcnt = (int*)sA;           // 2,500 B
    for (int i = t; i < NBUCK; i += 256) lcnt[i] = 0;
    __syncthreads();
    const int c = blockIdx.x, e0 = c * ECH;
    for (int e = e0 + t; e < e0 + ECH; e += 256) {
      const int d = dst[e];
      const int r = atomicAdd(&lcnt[d >> 6], 1);   // LDS atomic only
      pk[e] = ((d >> 6) << 17) | ((d & 63) << 11) | r;
    }
    __syncthreads();
    for (int i = t; i < NBUCK; i += 256) cnt2[c * NBUCK + i] = lcnt[i];
    return;
  }

  const int row0 = blockIdx.x * 32;

  // stage A: 32 rows x 128 k, fp32 -> bf16 (coalesced float4 reads)
  {
    const int kq = t & 31;            // k = kq*4
    const int rb = (t >> 5) * 4;      // 4 rows per thread
    #pragma unroll
    for (int i = 0; i < 4; ++i) {
      const int r = rb + i;
      const float4 f = *(const float4*)&feat[(long)(row0 + r) * 128 + kq * 4];
      const unsigned lo = (unsigned)f2bf(f.x) | ((unsigned)f2bf(f.y) << 16);
      const unsigned hi = (unsigned)f2bf(f.z) | ((unsigned)f2bf(f.w) << 16);
      *(uint2*)&sA[r * KP + kq * 4] = make_uint2(lo, hi);
    }
  }

  const int w = t >> 6, lane = t & 63;
  const int c15 = lane & 15, q = lane >> 4;

  // B frags for both weight matrices: wave w owns n-tiles {2w, 2w+1}
  short8 bfr0[4][2], bfr1[4][2];
  #pragma unroll
  for (int kc = 0; kc < 4; ++kc)
    #pragma unroll
    for (int nt = 0; nt < 2; ++nt) {
      const int n = (w * 2 + nt) * 16 + c15;
      bfr0[kc][nt] = *(const short8*)&wt[n * 128 + kc * 32 + q * 8];
      bfr1[kc][nt] = *(const short8*)&wt[16384 + n * 128 + kc * 32 + q * 8];
    }
  __syncthreads();

  floatx4 acc0[2][2], acc1[2][2];
  #pragma unroll
  for (int mt = 0; mt < 2; ++mt)
    #pragma unroll
    for (int nt = 0; nt < 2; ++nt) {
      acc0[mt][nt] = (floatx4){0.f, 0.f, 0.f, 0.f};
      acc1[mt][nt] = (floatx4){0.f, 0.f, 0.f, 0.f};
    }
  #pragma unroll
  for (int kc = 0; kc < 4; ++kc)
    #pragma unroll
    for (int mt = 0; mt < 2; ++mt) {
      const short8 afr = *(const short8*)&sA[(mt * 16 + c15) * KP + kc * 32 + q * 8];
      acc0[mt][0] = __builtin_amdgcn_mfma_f32_16x16x32_bf16(afr, bfr0[kc][0], acc0[mt][0], 0, 0, 0);
      acc0[mt][1] = __builtin_amdgcn_mfma_f32_16x16x32_bf16(afr, bfr0[kc][1], acc0[mt][1], 0, 0, 0);
      acc1[mt][0] = __builtin_amdgcn_mfma_f32_16x16x32_bf16(afr, bfr1[kc][0], acc1[mt][0], 0, 0, 0);
      acc1[mt][1] = __builtin_amdgcn_mfma_f32_16x16x32_bf16(afr, bfr1[kc][1], acc1[mt][1], 0, 0, 0);
    }

  const int orow = t >> 3, seg = t & 7;
  const int grow = row0 + orow;

  // ---- pass 0: xh + alpha from acc0 ----
  #pragma unroll
  for (int mt = 0; mt < 2; ++mt)
    #pragma unroll
    for (int nt = 0; nt < 2; ++nt) {
      const int col = (w * 2 + nt) * 16 + c15;
      #pragma unroll
      for (int r = 0; r < 4; ++r)
        sD[(mt * 16 + q * 4 + r) * 132 + col] = acc0[mt][nt][r];
    }
  __syncthreads();
  {
    #pragma unroll
    for (int i = 0; i < 2; ++i) {     // 8 cols per iter
      const float4 v0 = *(const float4*)&sD[orow * 132 + seg * 16 + i * 8];
      const float4 v1 = *(const float4*)&sD[orow * 132 + seg * 16 + i * 8 + 4];
      uint4 u;
      u.x = (unsigned)f2bf(v0.x) | ((unsigned)f2bf(v0.y) << 16);
      u.y = (unsigned)f2bf(v0.z) | ((unsigned)f2bf(v0.w) << 16);
      u.z = (unsigned)f2bf(v1.x) | ((unsigned)f2bf(v1.y) << 16);
      u.w = (unsigned)f2bf(v1.z) | ((unsigned)f2bf(v1.w) << 16);
      *(uint4*)&xh[(long)grow * 128 + seg * 16 + i * 8] = u;
    }
    // fused alpha epilogue: thread = (node orow, head seg); one 16-dot each.
    const int h = seg;
    float sl = 0.f, sr = 0.f;
    #pragma unroll
    for (int c4 = 0; c4 < 4; ++c4) {
      const float4 xv = *(const float4*)&sD[orow * 132 + h * 16 + c4 * 4];
      const float4 lv = *(const float4*)&attl[h * 16 + c4 * 4];
      const float4 rv = *(const float4*)&attr[h * 16 + c4 * 4];
      sl += xv.x * lv.x + xv.y * lv.y + xv.z * lv.z + xv.w * lv.w;
      sr += xv.x * rv.x + xv.y * rv.y + xv.z * rv.z + xv.w * rv.w;
    }
    al[(long)grow * 8 + h] = sl;
    ar[(long)grow * 8 + h] = sr;
  }
  __syncthreads();

  // ---- pass 1: outp from acc1 ----
  #pragma unroll
  for (int mt = 0; mt < 2; ++mt)
    #pragma unroll
    for (int nt = 0; nt < 2; ++nt) {
      const int col = (w * 2 + nt) * 16 + c15;
      #pragma unroll
      for (int r = 0; r < 4; ++r)
        sD[(mt * 16 + q * 4 + r) * 132 + col] = acc1[mt][nt][r];
    }
  __syncthreads();
  #pragma unroll
  for (int i = 0; i < 4; ++i) {
    const float4 v = *(const float4*)&sD[orow * 132 + seg * 16 + i * 4];
    *(float4*)&outp[(long)grow * 128 + seg * 16 + i * 4] = v;
  }
}

// Per-bucket scan over 512 chunk-counts -> pre2T[b][c] (coalesced) + total[b].
__global__ __launch_bounds__(512) void k_scan2a(
    const int* __restrict__ cnt2, int* __restrict__ pre2T, int* __restrict__ total)
{
  __shared__ int sd[NCH];
  const int b = blockIdx.x;
  const int t = threadIdx.x;
  const int v = cnt2[t * NBUCK + b];   // strided read (one per thread)
  sd[t] = v;
  __syncthreads();
  #pragma unroll
  for (int off = 1; off < NCH; off <<= 1) {
    const int add = (t >= off) ? sd[t - off] : 0;
    __syncthreads();
    sd[t] += add;
    __syncthreads();
  }
  pre2T[b * NCH + t] = sd[t] - v;
  if (t == NCH - 1) total[b] = sd[t];
}

// One thread per edge: slot fully precomputed against FIXED bucket bases
// (b*MAXB) — no global scan needed. Single 8-byte scatter einfo[p].
__global__ __launch_bounds__(256) void k_place(
    const int* __restrict__ pk, const int* __restrict__ src,
    const float* __restrict__ ew,
    const int* __restrict__ pre2T, uint2* __restrict__ einfo)
{
  const int e = blockIdx.x * 256 + threadIdx.x;
  if (e >= N_EDGES) return;
  const int k = pk[e];
  const int b = k >> 17, dl = (k >> 11) & 63, r = k & 2047;
  const int c = e / ECH;
  const int p = b * MAXB + pre2T[b * NCH + c] + r;
  einfo[p] = make_uint2(((unsigned)src[e] << 6) | (unsigned)dl,
                        __float_as_uint(ew[e]));
}

// FUSED edge+aggregate: one 1024-thread block per bucket.
//  phase 1: coalesced einfo read -> LDS, 64-bin count.
//  phase 2: wave-0 shuffle scan of bins.
//  phase 3: exp(logits) (al gathered L2-hot, ar staged in LDS), counting-sort
//           INTO LDS (sS/sP stay local — no global psrc/pexph round-trip).
//  phase 4: per-node register aggregation (round-1-proven structure): wave v
//           owns 4 nodes; acc += pexp*x, ssum += pexp; normalize, ELU,
//           residual RMW on outp. 625 blocks x 16 waves = 10K gather waves.
// pexp: no max subtraction (logits bounded ~|4|, softmax shift-invariant —
// validated in earlier rounds).
__global__ __launch_bounds__(1024, 4) void k_edgeagg(
    const int* __restrict__ total, const uint2* __restrict__ einfo,
    const float* __restrict__ al, const float* __restrict__ ar,
    const unsigned short* __restrict__ xh, float* __restrict__ outp)
{
  __shared__ uint2 sE[MAXB];               // 12,288 B
  __shared__ unsigned short sP[MAXB * 8];  // 24,576 B (sorted pexp, bf16)
  __shared__ int sS[MAXB];                 //  6,144 B (sorted src ids)
  __shared__ float sAr[512];               //  2,048 B
  __shared__ int bcnt[64], bbase[64], bpos[64];
  const int b = blockIdx.x;
  const int cntb = total[b];
  const int t = threadIdx.x;
  if (t < 64) bcnt[t] = 0;
  if (t < 512) sAr[t] = ar[((long)(b << 6)) * 8 + t];
  __syncthreads();
  const long e0 = (long)b * MAXB;
  for (int i = t; i < cntb; i += 1024) {
    const uint2 m = einfo[e0 + i];
    sE[i] = m;
    atomicAdd(&bcnt[m.x & 63], 1);   // LDS atomic only
  }
  __syncthreads();
  if (t < 64) {            // wave 0: inclusive shuffle scan of 64 bins
    const int v = bcnt[t];
    int incl = v;
    #pragma unroll
    for (int off = 1; off < 64; off <<= 1) {
      const int n = __shfl_up(incl, off, 64);
      if (t >= off) incl += n;
    }
    bbase[t] = incl - v;
    bpos[t] = 0;
  }
  __syncthreads();
  for (int i = t; i < cntb; i += 1024) {
    const uint2 m = sE[i];
    const int dl = m.x & 63;
    const int s = (int)(m.x >> 6);
    const float w = __uint_as_float(m.y);
    const float4 l0 = *(const float4*)&al[(long)s * 8];
    const float4 l1 = *(const float4*)&al[(long)s * 8 + 4];
    const float* arr = &sAr[dl * 8];
    float lv[8] = {l0.x + arr[0], l0.y + arr[1], l0.z + arr[2], l0.w + arr[3],
                   l1.x + arr[4], l1.y + arr[5], l1.z + arr[6], l1.w + arr[7]};
    #pragma unroll
    for (int h = 0; h < 8; ++h) {
      float a = w * lv[h];
      a = (a >= 0.f) ? a : 0.2f * a;   // leaky_relu(0.2)
      lv[h] = __expf(a);
    }
    const int r = atomicAdd(&bpos[dl], 1);   // LDS atomic only
    const int qq = bbase[dl] + r;
    sS[qq] = s;
    uint4 u;
    u.x = (unsigned)f2bf(lv[0]) | ((unsigned)f2bf(lv[1]) << 16);
    u.y = (unsigned)f2bf(lv[2]) | ((unsigned)f2bf(lv[3]) << 16);
    u.z = (unsigned)f2bf(lv[4]) | ((unsigned)f2bf(lv[5]) << 16);
    u.w = (unsigned)f2bf(lv[6]) | ((unsigned)f2bf(lv[7]) << 16);
    *(uint4*)&sP[qq * 8] = u;
  }
  __syncthreads();

  // phase 4: aggregation. wave wv handles nodes wv*4 .. wv*4+3.
  const int wv = t >> 6, lane = t & 63;
  const int h = lane >> 3;
  const int co = lane * 2;
  #pragma unroll
  for (int j = 0; j < 4; ++j) {
    const int dl = wv * 4 + j;
    const int start = bbase[dl];
    const int end = start + bcnt[dl];
    if (end <= start) continue;   // out already holds residual; elu(0)=0

    float2 a0 = {0.f, 0.f}, a1 = {0.f, 0.f}, a2 = {0.f, 0.f}, a3 = {0.f, 0.f};
    float s0s = 0.f, s1s = 0.f, s2s = 0.f, s3s = 0.f;
    int p = start;
    for (; p + 4 <= end; p += 4) {
      const int s0 = sS[p + 0], s1 = sS[p + 1];
      const int s2 = sS[p + 2], s3 = sS[p + 3];
      const float e0v = bf2f(sP[(p + 0) * 8 + h]);
      const float e1v = bf2f(sP[(p + 1) * 8 + h]);
      const float e2v = bf2f(sP[(p + 2) * 8 + h]);
      const float e3v = bf2f(sP[(p + 3) * 8 + h]);
      const unsigned v0 = *(const unsigned*)&xh[(long)s0 * 128 + co];
      const unsigned v1 = *(const unsigned*)&xh[(long)s1 * 128 + co];
      const unsigned v2 = *(const unsigned*)&xh[(long)s2 * 128 + co];
      const unsigned v3 = *(const unsigned*)&xh[(long)s3 * 128 + co];
      a0.x = fmaf(bflo(v0), e0v, a0.x); a0.y = fmaf(bfhi(v0), e0v, a0.y); s0s += e0v;
      a1.x = fmaf(bflo(v1), e1v, a1.x); a1.y = fmaf(bfhi(v1), e1v, a1.y); s1s += e1v;
      a2.x = fmaf(bflo(v2), e2v, a2.x); a2.y = fmaf(bfhi(v2), e2v, a2.y); s2s += e2v;
      a3.x = fmaf(bflo(v3), e3v, a3.x); a3.y = fmaf(bfhi(v3), e3v, a3.y); s3s += e3v;
    }
    for (; p < end; ++p) {
      const int s = sS[p];
      const float ev = bf2f(sP[p * 8 + h]);
      const unsigned v = *(const unsigned*)&xh[(long)s * 128 + co];
      a0.x = fmaf(bflo(v), ev, a0.x);
      a0.y = fmaf(bfhi(v), ev, a0.y);
      s0s += ev;
    }
    const float rs = 1.0f / ((s0s + s1s) + (s2s + s3s));
    const float ax = ((a0.x + a1.x) + (a2.x + a3.x)) * rs;
    const float ay = ((a0.y + a1.y) + (a2.y + a3.y)) * rs;

    const long dnode = (long)(b << 6) + dl;
    float2 o = *(float2*)&outp[dnode * 128 + co];
    o.x += (ax > 0.f) ? ax : expm1f(ax);
    o.y += (ay > 0.f) ? ay : expm1f(ay);
    *(float2*)&outp[dnode * 128 + co] = o;
  }
}

extern "C" void kernel_launch(void* const* d_in, const int* in_sizes, int n_in,
                              void* d_out, int out_size, void* d_ws, size_t ws_size,
                              hipStream_t stream) {
  const float* feat = (const float*)d_in[0];
  const int*   eidx = (const int*)d_in[1];
  const float* ew   = (const float*)d_in[2];
  const float* Wlin = (const float*)d_in[3];
  const float* attl = (const float*)d_in[4];
  const float* attr = (const float*)d_in[5];
  const float* Wres = (const float*)d_in[6];
  float* outp = (float*)d_out;

  float* ws = (float*)d_ws;
  unsigned short* xh = (unsigned short*)ws;
  float* al   = ws + 5120000;
  float* ar   = ws + 5440000;
  int*   pk   = (int*)(ws + 5760000);
  uint2* einfo = (uint2*)(ws + 6500000);   // NBUCK*MAXB uint2
  int*   cnt2 = (int*)(ws + 8500000);
  int*   pre2T = (int*)(ws + 8900000);
  int*   total = (int*)(ws + 9300000);
  unsigned short* wt = (unsigned short*)(ws + 12800000);

  const int* src = eidx;
  const int* dst = eidx + N_EDGES;

  dim3 pgrid(128, 2);
  k_prep<<<pgrid, 128, 0, stream>>>(Wlin, Wres, wt);
  dim3 ggrid(NBG, 2);   // y=0 dual GEMM + alpha, y=1 count/rank
  k_gemm<<<ggrid, 256, 0, stream>>>(feat, wt, xh, outp, attl, attr, al, ar,
                                    dst, pk, cnt2);
  k_scan2a<<<NBUCK, NCH, 0, stream>>>(cnt2, pre2T, total);
  k_place<<<N_EDGES / 256, 256, 0, stream>>>(pk, src, ew, pre2T, einfo);
  k_edgeagg<<<NBUCK, 1024, 0, stream>>>(total, einfo, al, ar, xh, outp);
}

// Round 7
// 150.049 us; speedup vs baseline: 4.6725x; 1.0466x over previous
//
#include <hip/hip_runtime.h>
#include <math.h>

#define N_NODES 40000
#define N_EDGES 640000
#define D 128
#define H 8
#define C 16
#define NBG 1250     // 40000/32 exactly
#define KP 136       // sA k-stride (bf16 elems)
#define NBUCK 625    // 64-node buckets: bucket = dst >> 6 (40000 = 625*64)
#define NCH 512      // chunks (1250 edges each)
#define ECH 1250     // edges per chunk (512*1250 = 640000)
#define CAP 12       // per-(bucket,chunk) slot capacity; Poisson(2) tail ~2e-7
#define SLOTS (NCH * CAP)   // 6144 slots per bucket
#define MAXB 1536    // bucket-size bound (mean 1024, sigma~32; 16-sigma)
#define OVCAP 4096   // overflow list capacity

typedef __attribute__((ext_vector_type(8))) short short8;   // 8 bf16 (4 VGPRs)
typedef __attribute__((ext_vector_type(4))) float floatx4;  // MFMA C/D

// ws layout (float offsets):
//  xh    : 0          .. 2,560,000   (N*128 bf16 stored as ushort)
//  al    : 5,120,000  .. 5,440,000   (N*8)
//  ar    : 5,440,000  .. 5,760,000   (N*8)
//  einfo : 6,000,000  .. 13,680,000  (NBUCK*SLOTS uint2 fixed cells;
//                                     einfo[(b*512+c)*12+r]={(src<<6)|dl, ew})
//  cnt2  : 14,000,000 .. 14,320,000  ([512][625] ints, raw per-cell counts)
//  ovfn  : 14,400,000 (1 int)  ovf: 14,400,064 .. +4*OVCAP (uint4 entries)
//  wt    : 15,000,000 .. +16,384 (2x 128x128 bf16 transposed weights)

__device__ __forceinline__ unsigned short f2bf(float f) {
  const unsigned u = __float_as_uint(f);
  return (unsigned short)((u + 0x7FFFu + ((u >> 16) & 1u)) >> 16);  // RNE
}
__device__ __forceinline__ float bflo(unsigned p) {
  return __uint_as_float(p << 16);
}
__device__ __forceinline__ float bfhi(unsigned p) {
  return __uint_as_float(p & 0xFFFF0000u);
}
__device__ __forceinline__ float bf2f(unsigned short u) {
  return __uint_as_float((unsigned)u << 16);
}

// Pre-transpose W (fp32 [k][n]) -> wt (bf16 [g][n][k]). Also zeroes the
// overflow counter (runs before k_gemm in-stream).
__global__ void k_prep(const float* __restrict__ Wlin,
                       const float* __restrict__ Wres,
                       unsigned short* __restrict__ wt, int* __restrict__ ovfn)
{
  const int n = blockIdx.x, k = threadIdx.x, g = blockIdx.y;
  if (n == 0 && g == 0 && k == 0) *ovfn = 0;
  const float* W = g ? Wres : Wlin;
  wt[((g * 128 + n) * 128) + k] = f2bf(W[(long)k * 128 + n]);
}

// MFMA bf16 GEMM, 32-row blocks, BOTH weight matrices per block.
// blockIdx.y==0: xh=bf16(feat@Wlin) + fused alpha epilogue, outp=feat@Wres.
// blockIdx.y==1: count pass that scatters einfo DIRECTLY into fixed
//   per-(bucket,chunk) cells: slot=(b*512+c)*12 + r (r = LDS rank). No pk,
//   no scan, no place kernel. Rare r>=12 edges go to a global overflow list.
__global__ __launch_bounds__(256, 4) void k_gemm(
    const float* __restrict__ feat, const unsigned short* __restrict__ wt,
    unsigned short* __restrict__ xh, float* __restrict__ outp,
    const float* __restrict__ attl, const float* __restrict__ attr,
    float* __restrict__ al, float* __restrict__ ar,
    const int* __restrict__ src, const int* __restrict__ dst,
    const float* __restrict__ ew, uint2* __restrict__ einfo,
    int* __restrict__ cnt2, int* __restrict__ ovfn, uint4* __restrict__ ovf)
{
  __shared__ short sA[32 * KP];     // 8,704 B
  __shared__ float sD[32 * 132];    // 16,896 B
  const int t = threadIdx.x;

  if (blockIdx.y == 1) {            // fused count + direct-scatter pass
    if (blockIdx.x >= NCH) return;
    int* lcnt = (int*)sA;           // 2,500 B
    for (int i = t; i < NBUCK; i += 256) lcnt[i] = 0;
    __syncthreads();
    const int c = blockIdx.x, e0 = c * ECH;
    for (int e = e0 + t; e < e0 + ECH; e += 256) {
      const int d = dst[e];
      const int b = d >> 6, dl = d & 63;
      const int r = atomicAdd(&lcnt[b], 1);   // LDS atomic only
      const unsigned pay = ((unsigned)src[e] << 6) | (unsigned)dl;
      const unsigned wbits = __float_as_uint(ew[e]);
      if (r < CAP) {
        einfo[((long)b * NCH + c) * CAP + r] = make_uint2(pay, wbits);
      } else {                                 // ~0.06 expected edges total
        const int oi = atomicAdd(ovfn, 1);
        if (oi < OVCAP)
          ovf[oi] = make_uint4((unsigned)b, (unsigned)dl,
                               (unsigned)src[e], wbits);
      }
    }
    __syncthreads();
    for (int i = t; i < NBUCK; i += 256) cnt2[c * NBUCK + i] = lcnt[i];
    return;
  }

  const int row0 = blockIdx.x * 32;

  // stage A: 32 rows x 128 k, fp32 -> bf16 (coalesced float4 reads)
  {
    const int kq = t & 31;            // k = kq*4
    const int rb = (t >> 5) * 4;      // 4 rows per thread
    #pragma unroll
    for (int i = 0; i < 4; ++i) {
      const int r = rb + i;
      const float4 f = *(const float4*)&feat[(long)(row0 + r) * 128 + kq * 4];
      const unsigned lo = (unsigned)f2bf(f.x) | ((unsigned)f2bf(f.y) << 16);
      const unsigned hi = (unsigned)f2bf(f.z) | ((unsigned)f2bf(f.w) << 16);
      *(uint2*)&sA[r * KP + kq * 4] = make_uint2(lo, hi);
    }
  }

  const int w = t >> 6, lane = t & 63;
  const int c15 = lane & 15, q = lane >> 4;

  // B frags for both weight matrices: wave w owns n-tiles {2w, 2w+1}
  short8 bfr0[4][2], bfr1[4][2];
  #pragma unroll
  for (int kc = 0; kc < 4; ++kc)
    #pragma unroll
    for (int nt = 0; nt < 2; ++nt) {
      const int n = (w * 2 + nt) * 16 + c15;
      bfr0[kc][nt] = *(const short8*)&wt[n * 128 + kc * 32 + q * 8];
      bfr1[kc][nt] = *(const short8*)&wt[16384 + n * 128 + kc * 32 + q * 8];
    }
  __syncthreads();

  floatx4 acc0[2][2], acc1[2][2];
  #pragma unroll
  for (int mt = 0; mt < 2; ++mt)
    #pragma unroll
    for (int nt = 0; nt < 2; ++nt) {
      acc0[mt][nt] = (floatx4){0.f, 0.f, 0.f, 0.f};
      acc1[mt][nt] = (floatx4){0.f, 0.f, 0.f, 0.f};
    }
  #pragma unroll
  for (int kc = 0; kc < 4; ++kc)
    #pragma unroll
    for (int mt = 0; mt < 2; ++mt) {
      const short8 afr = *(const short8*)&sA[(mt * 16 + c15) * KP + kc * 32 + q * 8];
      acc0[mt][0] = __builtin_amdgcn_mfma_f32_16x16x32_bf16(afr, bfr0[kc][0], acc0[mt][0], 0, 0, 0);
      acc0[mt][1] = __builtin_amdgcn_mfma_f32_16x16x32_bf16(afr, bfr0[kc][1], acc0[mt][1], 0, 0, 0);
      acc1[mt][0] = __builtin_amdgcn_mfma_f32_16x16x32_bf16(afr, bfr1[kc][0], acc1[mt][0], 0, 0, 0);
      acc1[mt][1] = __builtin_amdgcn_mfma_f32_16x16x32_bf16(afr, bfr1[kc][1], acc1[mt][1], 0, 0, 0);
    }

  const int orow = t >> 3, seg = t & 7;
  const int grow = row0 + orow;

  // ---- pass 0: xh + alpha from acc0 ----
  #pragma unroll
  for (int mt = 0; mt < 2; ++mt)
    #pragma unroll
    for (int nt = 0; nt < 2; ++nt) {
      const int col = (w * 2 + nt) * 16 + c15;
      #pragma unroll
      for (int r = 0; r < 4; ++r)
        sD[(mt * 16 + q * 4 + r) * 132 + col] = acc0[mt][nt][r];
    }
  __syncthreads();
  {
    #pragma unroll
    for (int i = 0; i < 2; ++i) {     // 8 cols per iter
      const float4 v0 = *(const float4*)&sD[orow * 132 + seg * 16 + i * 8];
      const float4 v1 = *(const float4*)&sD[orow * 132 + seg * 16 + i * 8 + 4];
      uint4 u;
      u.x = (unsigned)f2bf(v0.x) | ((unsigned)f2bf(v0.y) << 16);
      u.y = (unsigned)f2bf(v0.z) | ((unsigned)f2bf(v0.w) << 16);
      u.z = (unsigned)f2bf(v1.x) | ((unsigned)f2bf(v1.y) << 16);
      u.w = (unsigned)f2bf(v1.z) | ((unsigned)f2bf(v1.w) << 16);
      *(uint4*)&xh[(long)grow * 128 + seg * 16 + i * 8] = u;
    }
    // fused alpha epilogue: thread = (node orow, head seg); one 16-dot each.
    const int h = seg;
    float sl = 0.f, sr = 0.f;
    #pragma unroll
    for (int c4 = 0; c4 < 4; ++c4) {
      const float4 xv = *(const float4*)&sD[orow * 132 + h * 16 + c4 * 4];
      const float4 lv = *(const float4*)&attl[h * 16 + c4 * 4];
      const float4 rv = *(const float4*)&attr[h * 16 + c4 * 4];
      sl += xv.x * lv.x + xv.y * lv.y + xv.z * lv.z + xv.w * lv.w;
      sr += xv.x * rv.x + xv.y * rv.y + xv.z * rv.z + xv.w * rv.w;
    }
    al[(long)grow * 8 + h] = sl;
    ar[(long)grow * 8 + h] = sr;
  }
  __syncthreads();

  // ---- pass 1: outp from acc1 ----
  #pragma unroll
  for (int mt = 0; mt < 2; ++mt)
    #pragma unroll
    for (int nt = 0; nt < 2; ++nt) {
      const int col = (w * 2 + nt) * 16 + c15;
      #pragma unroll
      for (int r = 0; r < 4; ++r)
        sD[(mt * 16 + q * 4 + r) * 132 + col] = acc1[mt][nt][r];
    }
  __syncthreads();
  #pragma unroll
  for (int i = 0; i < 4; ++i) {
    const float4 v = *(const float4*)&sD[orow * 132 + seg * 16 + i * 4];
    *(float4*)&outp[(long)grow * 128 + seg * 16 + i * 4] = v;
  }
}

// FUSED edge+aggregate: one 1024-thread block per bucket.
//  stage: clamped per-chunk counts (scnt), ar rows -> LDS.
//  phase 1: coalesced sweep of the bucket's 6144 fixed slots; valid slots
//           (r < scnt[c]) compacted into sE via LDS cursor + 64-bin count;
//           overflow list scanned (normally empty).
//  phase 2: wave-0 shuffle scan of bins.
//  phase 3: exp(logits) (al gathered L2-hot, ar in LDS), counting-sort in LDS.
//  phase 4: per-node register aggregation (round-1-proven): wave wv owns 4
//           nodes; acc += pexp*x, ssum += pexp; normalize, ELU, residual RMW.
// pexp: no max subtraction (logits bounded ~|4|, softmax shift-invariant —
// validated in earlier rounds).
__global__ __launch_bounds__(1024, 4) void k_edgeagg(
    const int* __restrict__ cnt2, const uint2* __restrict__ einfo,
    const int* __restrict__ ovfn, const uint4* __restrict__ ovf,
    const float* __restrict__ al, const float* __restrict__ ar,
    const unsigned short* __restrict__ xh, float* __restrict__ outp)
{
  __shared__ uint2 sE[MAXB];               // 12,288 B
  __shared__ unsigned short sP[MAXB * 8];  // 24,576 B (sorted pexp, bf16)
  __shared__ int sS[MAXB];                 //  6,144 B (sorted src ids)
  __shared__ float sAr[512];               //  2,048 B
  __shared__ int scnt[NCH];                //  2,048 B (clamped counts)
  __shared__ int bcnt[64], bbase[64], bpos[64];
  __shared__ int nE;
  const int b = blockIdx.x;
  const int t = threadIdx.x;
  if (t < 64) bcnt[t] = 0;
  if (t == 64) nE = 0;
  if (t < 512) sAr[t] = ar[((long)(b << 6)) * 8 + t];
  else scnt[t - 512] = min(cnt2[(t - 512) * NBUCK + b], CAP);
  __syncthreads();

  // phase 1: coalesced slot sweep + compaction
  const long base = (long)b * SLOTS;
  for (int i = t; i < SLOTS; i += 1024) {
    const int c = i / CAP;
    const int r = i - c * CAP;
    if (r < scnt[c]) {
      const uint2 m = einfo[base + i];
      const int k = atomicAdd(&nE, 1);     // LDS atomic only
      sE[k] = m;
      atomicAdd(&bcnt[m.x & 63], 1);
    }
  }
  const int no = *ovfn;                    // normally 0
  for (int i = t; i < no; i += 1024) {
    const uint4 o = ovf[i];
    if ((int)o.x == b) {
      const int k = atomicAdd(&nE, 1);
      sE[k] = make_uint2((o.z << 6) | o.y, o.w);
      atomicAdd(&bcnt[o.y], 1);
    }
  }
  __syncthreads();
  const int cntb = nE;

  if (t < 64) {            // phase 2: wave 0 inclusive shuffle scan of 64 bins
    const int v = bcnt[t];
    int incl = v;
    #pragma unroll
    for (int off = 1; off < 64; off <<= 1) {
      const int n = __shfl_up(incl, off, 64);
      if (t >= off) incl += n;
    }
    bbase[t] = incl - v;
    bpos[t] = 0;
  }
  __syncthreads();

  // phase 3: exp + counting sort into LDS
  for (int i = t; i < cntb; i += 1024) {
    const uint2 m = sE[i];
    const int dl = m.x & 63;
    const int s = (int)(m.x >> 6);
    const float w = __uint_as_float(m.y);
    const float4 l0 = *(const float4*)&al[(long)s * 8];
    const float4 l1 = *(const float4*)&al[(long)s * 8 + 4];
    const float* arr = &sAr[dl * 8];
    float lv[8] = {l0.x + arr[0], l0.y + arr[1], l0.z + arr[2], l0.w + arr[3],
                   l1.x + arr[4], l1.y + arr[5], l1.z + arr[6], l1.w + arr[7]};
    #pragma unroll
    for (int h = 0; h < 8; ++h) {
      float a = w * lv[h];
      a = (a >= 0.f) ? a : 0.2f * a;   // leaky_relu(0.2)
      lv[h] = __expf(a);
    }
    const int r = atomicAdd(&bpos[dl], 1);   // LDS atomic only
    const int qq = bbase[dl] + r;
    sS[qq] = s;
    uint4 u;
    u.x = (unsigned)f2bf(lv[0]) | ((unsigned)f2bf(lv[1]) << 16);
    u.y = (unsigned)f2bf(lv[2]) | ((unsigned)f2bf(lv[3]) << 16);
    u.z = (unsigned)f2bf(lv[4]) | ((unsigned)f2bf(lv[5]) << 16);
    u.w = (unsigned)f2bf(lv[6]) | ((unsigned)f2bf(lv[7]) << 16);
    *(uint4*)&sP[qq * 8] = u;
  }
  __syncthreads();

  // phase 4: aggregation. wave wv handles nodes wv*4 .. wv*4+3.
  const int wv = t >> 6, lane = t & 63;
  const int h = lane >> 3;
  const int co = lane * 2;
  #pragma unroll
  for (int j = 0; j < 4; ++j) {
    const int dl = wv * 4 + j;
    const int start = bbase[dl];
    const int end = start + bcnt[dl];
    if (end <= start) continue;   // out already holds residual; elu(0)=0

    float2 a0 = {0.f, 0.f}, a1 = {0.f, 0.f}, a2 = {0.f, 0.f}, a3 = {0.f, 0.f};
    float s0s = 0.f, s1s = 0.f, s2s = 0.f, s3s = 0.f;
    int p = start;
    for (; p + 4 <= end; p += 4) {
      const int s0 = sS[p + 0], s1 = sS[p + 1];
      const int s2 = sS[p + 2], s3 = sS[p + 3];
      const float e0v = bf2f(sP[(p + 0) * 8 + h]);
      const float e1v = bf2f(sP[(p + 1) * 8 + h]);
      const float e2v = bf2f(sP[(p + 2) * 8 + h]);
      const float e3v = bf2f(sP[(p + 3) * 8 + h]);
      const unsigned v0 = *(const unsigned*)&xh[(long)s0 * 128 + co];
      const unsigned v1 = *(const unsigned*)&xh[(long)s1 * 128 + co];
      const unsigned v2 = *(const unsigned*)&xh[(long)s2 * 128 + co];
      const unsigned v3 = *(const unsigned*)&xh[(long)s3 * 128 + co];
      a0.x = fmaf(bflo(v0), e0v, a0.x); a0.y = fmaf(bfhi(v0), e0v, a0.y); s0s += e0v;
      a1.x = fmaf(bflo(v1), e1v, a1.x); a1.y = fmaf(bfhi(v1), e1v, a1.y); s1s += e1v;
      a2.x = fmaf(bflo(v2), e2v, a2.x); a2.y = fmaf(bfhi(v2), e2v, a2.y); s2s += e2v;
      a3.x = fmaf(bflo(v3), e3v, a3.x); a3.y = fmaf(bfhi(v3), e3v, a3.y); s3s += e3v;
    }
    for (; p < end; ++p) {
      const int s = sS[p];
      const float ev = bf2f(sP[p * 8 + h]);
      const unsigned v = *(const unsigned*)&xh[(long)s * 128 + co];
      a0.x = fmaf(bflo(v), ev, a0.x);
      a0.y = fmaf(bfhi(v), ev, a0.y);
      s0s += ev;
    }
    const float rs = 1.0f / ((s0s + s1s) + (s2s + s3s));
    const float ax = ((a0.x + a1.x) + (a2.x + a3.x)) * rs;
    const float ay = ((a0.y + a1.y) + (a2.y + a3.y)) * rs;

    const long dnode = (long)(b << 6) + dl;
    float2 o = *(float2*)&outp[dnode * 128 + co];
    o.x += (ax > 0.f) ? ax : expm1f(ax);
    o.y += (ay > 0.f) ? ay : expm1f(ay);
    *(float2*)&outp[dnode * 128 + co] = o;
  }
}

extern "C" void kernel_launch(void* const* d_in, const int* in_sizes, int n_in,
                              void* d_out, int out_size, void* d_ws, size_t ws_size,
                              hipStream_t stream) {
  const float* feat = (const float*)d_in[0];
  const int*   eidx = (const int*)d_in[1];
  const float* ew   = (const float*)d_in[2];
  const float* Wlin = (const float*)d_in[3];
  const float* attl = (const float*)d_in[4];
  const float* attr = (const float*)d_in[5];
  const float* Wres = (const float*)d_in[6];
  float* outp = (float*)d_out;

  float* ws = (float*)d_ws;
  unsigned short* xh = (unsigned short*)ws;
  float* al   = ws + 5120000;
  float* ar   = ws + 5440000;
  uint2* einfo = (uint2*)(ws + 6000000);   // NBUCK*SLOTS uint2 (30.7 MB)
  int*   cnt2 = (int*)(ws + 14000000);
  int*   ovfn = (int*)(ws + 14400000);
  uint4* ovf  = (uint4*)(ws + 14400064);
  unsigned short* wt = (unsigned short*)(ws + 15000000);

  const int* src = eidx;
  const int* dst = eidx + N_EDGES;

  dim3 pgrid(128, 2);
  k_prep<<<pgrid, 128, 0, stream>>>(Wlin, Wres, wt, ovfn);
  dim3 ggrid(NBG, 2);   // y=0 dual GEMM + alpha, y=1 count + direct scatter
  k_gemm<<<ggrid, 256, 0, stream>>>(feat, wt, xh, outp, attl, attr, al, ar,
                                    src, dst, ew, einfo, cnt2, ovfn, ovf);
  k_edgeagg<<<NBUCK, 1024, 0, stream>>>(cnt2, einfo, ovfn, ovf, al, ar,
                                        xh, outp);
}